// Round 1
// baseline (10198.965 us; speedup 1.0000x reference)
//
#include <hip/hip_runtime.h>
#include <hip/hip_bf16.h>

#define NB 32          // batch
#define C_IN 512
#define S_LEN 256
#define NITER 25
#define DM 2048
#define DM2 4096
#define DI 512
#define NH 8
#define HD 64
#define NS 512
#define MEM 25
#define OD 1000

#define OFF_C 800000   // NB*OD*NITER
#define OFF_S 801600   // + NB*2*NITER

// ---------------- setup kernels ----------------

__global__ void kinit(const float* __restrict__ sas, const float* __restrict__ strace,
                      const float* __restrict__ dec_a, const float* __restrict__ dec_o,
                      const int* __restrict__ iol, const int* __restrict__ ior,
                      float* __restrict__ ring, float* __restrict__ act,
                      float* __restrict__ daa, float* __restrict__ dba,
                      float* __restrict__ dao, float* __restrict__ dbo,
                      float* __restrict__ ra, float* __restrict__ ro) {
  int idx = blockIdx.x * 256 + threadIdx.x;
  // ring[slot=m][d][b] = start_trace[d][m]
  for (int i = idx; i < MEM * DM * NB; i += gridDim.x * 256) {
    int m = i / (DM * NB);
    int r = i - m * (DM * NB);
    int d = r >> 5;               // /NB
    ring[i] = strace[d * MEM + m];
  }
  if (idx < NB * DM) act[idx] = sas[idx & (DM - 1)];
  if (idx < NB * NS) {
    daa[idx] = 0.f; dba[idx] = 0.f;
    int k = idx & (NS - 1);
    dao[idx] = sas[iol[k]] * sas[ior[k]];
    dbo[idx] = 1.f;
  }
  if (idx < NS) {
    float ca = fminf(fmaxf(dec_a[idx], 0.f), 15.f);
    ra[idx] = expf(-ca);
    float co = fminf(fmaxf(dec_o[idx], 0.f), 15.f);
    ro[idx] = expf(-co);
  }
}

// kv[b,s,d] = sum_c x[b,c,s]*kv_w[c,d] + kv_b[d]   (pre-LN)
__global__ __launch_bounds__(256) void kkv(const float* __restrict__ x,
                                           const float* __restrict__ kvw,
                                           const float* __restrict__ kvb,
                                           float* __restrict__ kv) {
  __shared__ float xs[32][17];
  __shared__ float ws[32][64];
  int b = blockIdx.z, s0 = blockIdx.y * 16, d0 = blockIdx.x * 64;
  int t = threadIdx.x;
  int dd = t & 63, sq = t >> 6;   // thread: d=dd, s = s0 + sq + 4*i
  float acc[4] = {0.f, 0.f, 0.f, 0.f};
  for (int c0 = 0; c0 < C_IN; c0 += 32) {
    for (int e = t; e < 512; e += 256) {
      int cc = e >> 4, ss = e & 15;
      xs[cc][ss] = x[(b * C_IN + c0 + cc) * S_LEN + s0 + ss];
    }
    for (int e = t; e < 2048; e += 256) {
      int cc = e >> 6, d2 = e & 63;
      ws[cc][d2] = kvw[(c0 + cc) * DI + d0 + d2];
    }
    __syncthreads();
    #pragma unroll 8
    for (int cc = 0; cc < 32; cc++) {
      float w = ws[cc][dd];
      #pragma unroll
      for (int i = 0; i < 4; i++) acc[i] += xs[cc][sq + 4 * i] * w;
    }
    __syncthreads();
  }
  float bia = kvb[d0 + dd];
  #pragma unroll
  for (int i = 0; i < 4; i++)
    kv[(b * S_LEN + s0 + sq + 4 * i) * DI + d0 + dd] = acc[i] + bia;
}

// in-place LN over last dim (512) of each (b,s) row
__global__ __launch_bounds__(64) void kln(float* __restrict__ kv,
                                          const float* __restrict__ g,
                                          const float* __restrict__ bb) {
  int row = blockIdx.x;
  int lane = threadIdx.x;
  const int base = row * DI;
  float v[8], s = 0.f, sq = 0.f;
  #pragma unroll
  for (int i = 0; i < 8; i++) {
    v[i] = kv[base + lane + i * 64];
    s += v[i]; sq += v[i] * v[i];
  }
  for (int o = 32; o; o >>= 1) { s += __shfl_xor(s, o); sq += __shfl_xor(sq, o); }
  float mean = s * (1.f / DI);
  float var = sq * (1.f / DI) - mean * mean;
  float rstd = rsqrtf(fmaxf(var, 0.f) + 1e-5f);
  #pragma unroll
  for (int i = 0; i < 8; i++) {
    int d = lane + i * 64;
    kv[base + d] = (v[i] - mean) * rstd * g[d] + bb[d];
  }
}

// K/V = kv @ wk/wv^T + b
__global__ __launch_bounds__(256) void kkvproj(const float* __restrict__ kv,
                                               const float* __restrict__ aw,
                                               const float* __restrict__ ab,
                                               float* __restrict__ Kb,
                                               float* __restrict__ Vb) {
  __shared__ float kt[32][33];
  __shared__ float wt[32][65];
  int r0 = blockIdx.x * 32, j0 = blockIdx.y * 64;
  int woff = 512 * (1 + blockIdx.z);
  float* out = (blockIdx.z == 0) ? Kb : Vb;
  int t = threadIdx.x;
  int j = t & 63, rq = t >> 6;
  float acc[8] = {0.f};
  for (int m0 = 0; m0 < DI; m0 += 32) {
    for (int e = t; e < 1024; e += 256) {
      int rr = e >> 5, mm = e & 31;
      kt[rr][mm] = kv[(r0 + rr) * DI + m0 + mm];
    }
    for (int e = t; e < 2048; e += 256) {
      int jj = e >> 5, mm = e & 31;
      wt[mm][jj] = aw[(woff + j0 + jj) * DI + m0 + mm];
    }
    __syncthreads();
    #pragma unroll 8
    for (int mm = 0; mm < 32; mm++) {
      float w = wt[mm][j];
      #pragma unroll
      for (int i = 0; i < 8; i++) acc[i] += kt[rq * 8 + i][mm] * w;
    }
    __syncthreads();
  }
  float bia = ab[woff + j0 + j];
  #pragma unroll
  for (int i = 0; i < 8; i++)
    out[(r0 + rq * 8 + i) * DI + j0 + j] = acc[i] + bia;
}

// tp1_w (25,128,2048) -> w1t[d][j][m]
__global__ __launch_bounds__(256) void ktr1(const float* __restrict__ w1, float* __restrict__ w1t) {
  __shared__ float tile[25][8][65];
  int d0 = blockIdx.x * 64, j0 = blockIdx.y * 8;
  int t = threadIdx.x;
  for (int e = t; e < 12800; e += 256) {
    int m = e >> 9;            // /512
    int rem = e & 511;
    int jj = rem >> 6, dd = rem & 63;
    tile[m][jj][dd] = w1[((m * 128) + j0 + jj) * DM + d0 + dd];
  }
  __syncthreads();
  for (int e = t; e < 12800; e += 256) {
    int dd = e / 200;
    int rem = e - dd * 200;
    int jj = rem / 25;
    int m = rem - jj * 25;
    w1t[(d0 + dd) * (128 * 25) + (j0 + jj) * 25 + m] = tile[m][jj][dd];
  }
}

// tp2_w (64,2,2048) -> w2t[d][j][k]
__global__ __launch_bounds__(256) void ktr2(const float* __restrict__ w2, float* __restrict__ w2t) {
  __shared__ float tile[128][65];
  int d0 = blockIdx.x * 64;
  int t = threadIdx.x;
  for (int e = t; e < 8192; e += 256) {
    int row = e >> 6, dd = e & 63;
    tile[row][dd] = w2[row * DM + d0 + dd];
  }
  __syncthreads();
  for (int e = t; e < 8192; e += 256) {
    int dd = e >> 7, row = e & 127;
    w2t[(d0 + dd) * 128 + row] = tile[row][dd];
  }
}

// ---------------- per-iteration kernels ----------------

// sync_a update + q = ((sync_a@q_w)+q_b)@wq^T + bq     (one block per b)
__global__ __launch_bounds__(256) void kq(const float* __restrict__ act,
                                          const float* __restrict__ daa_in, const float* __restrict__ dba_in,
                                          float* __restrict__ daa_out, float* __restrict__ dba_out,
                                          const float* __restrict__ ra,
                                          const int* __restrict__ ial, const int* __restrict__ iar,
                                          const float* __restrict__ qw, const float* __restrict__ qb,
                                          const float* __restrict__ aw, const float* __restrict__ ab,
                                          float* __restrict__ qbuf) {
  int b = blockIdx.x, t = threadIdx.x;
  __shared__ float sa[NS];
  __shared__ float t1[NS];
  for (int k = t; k < NS; k += 256) {
    float dn = ra[k] * daa_in[b * NS + k] + act[b * DM + ial[k]] * act[b * DM + iar[k]];
    float bn = ra[k] * dba_in[b * NS + k] + 1.f;
    daa_out[b * NS + k] = dn;
    dba_out[b * NS + k] = bn;
    sa[k] = dn / sqrtf(bn);
  }
  __syncthreads();
  for (int m = t; m < DI; m += 256) {
    float acc = qb[m];
    #pragma unroll 4
    for (int k = 0; k < NS; k++) acc += sa[k] * qw[k * DI + m];
    t1[m] = acc;
  }
  __syncthreads();
  for (int j = t; j < DI; j += 256) {
    float acc = ab[j];
    const float* wr = aw + j * DI;
    #pragma unroll 4
    for (int m = 0; m < DI; m++) acc += t1[m] * wr[m];
    qbuf[b * DI + j] = acc;
  }
}

// attention for one (h,b)
__global__ __launch_bounds__(256) void kattn(const float* __restrict__ qbuf,
                                             const float* __restrict__ Kb,
                                             const float* __restrict__ Vb,
                                             float* __restrict__ attnres) {
  int h = blockIdx.x, b = blockIdx.y, t = threadIdx.x;
  __shared__ float qs[HD];
  __shared__ float sc[S_LEN];
  __shared__ float red[8];
  __shared__ float part[4][HD];
  if (t < HD) qs[t] = qbuf[b * DI + h * HD + t];
  __syncthreads();
  {
    const float* kr = Kb + (b * S_LEN + t) * DI + h * HD;
    float a = 0.f;
    #pragma unroll
    for (int d = 0; d < HD; d++) a += qs[d] * kr[d];
    sc[t] = a * 0.125f;
  }
  __syncthreads();
  float m = sc[t];
  for (int o = 32; o; o >>= 1) m = fmaxf(m, __shfl_xor(m, o));
  if ((t & 63) == 0) red[t >> 6] = m;
  __syncthreads();
  m = fmaxf(fmaxf(red[0], red[1]), fmaxf(red[2], red[3]));
  float p = expf(sc[t] - m);
  float su = p;
  for (int o = 32; o; o >>= 1) su += __shfl_xor(su, o);
  if ((t & 63) == 0) red[4 + (t >> 6)] = su;
  sc[t] = p;
  __syncthreads();
  su = red[4] + red[5] + red[6] + red[7];
  {
    int d = t & 63, sg = t >> 6;
    const float* vb = Vb + b * S_LEN * DI + h * HD + d;
    float a = 0.f;
    for (int s = sg * 64; s < sg * 64 + 64; s++) a += sc[s] * vb[s * DI];
    part[sg][d] = a;
  }
  __syncthreads();
  if (t < HD)
    attnres[b * DI + h * HD + t] = (part[0][t] + part[1][t] + part[2][t] + part[3][t]) / su;
}

// attn2 = attnres @ attn_out_w^T + attn_out_b   (block per b)
__global__ __launch_bounds__(256) void kaout(const float* __restrict__ attnres,
                                             const float* __restrict__ aow,
                                             const float* __restrict__ aob,
                                             float* __restrict__ attn2) {
  int b = blockIdx.x, t = threadIdx.x;
  __shared__ float ar[DI];
  for (int k = t; k < DI; k += 256) ar[k] = attnres[b * DI + k];
  __syncthreads();
  for (int j = t; j < DI; j += 256) {
    float acc = aob[j];
    const float* wr = aow + j * DI;
    #pragma unroll 4
    for (int m = 0; m < DI; m++) acc += ar[m] * wr[m];
    attn2[b * DI + j] = acc;
  }
}

// syn GEMM partials: pre=[attn2, act] (K=2560), spp[ks][b][n]
__global__ __launch_bounds__(256) void ksyn(const float* __restrict__ attn2,
                                            const float* __restrict__ act,
                                            const float* __restrict__ synw,
                                            float* __restrict__ spp) {
  int nc = blockIdx.x, ks = blockIdx.y, t = threadIdx.x;
  int n = nc * 64 + (t & 63);
  int bg = t >> 6;
  __shared__ float xt[32 * 161];
  float acc[8] = {0.f};
  int kbase = ks * 640;
  for (int kt = 0; kt < 4; kt++) {
    int k0 = kbase + kt * 160;
    for (int e = t; e < 32 * 160; e += 256) {
      int bb = e / 160;
      int kk = e - bb * 160;
      int k = k0 + kk;
      xt[bb * 161 + kk] = (k < DI) ? attn2[bb * DI + k] : act[bb * DM + (k - DI)];
    }
    __syncthreads();
    #pragma unroll 4
    for (int kk = 0; kk < 160; kk++) {
      float w = synw[(k0 + kk) * DM2 + n];
      #pragma unroll
      for (int i = 0; i < 8; i++) acc[i] += xt[(bg * 8 + i) * 161 + kk] * w;
    }
    __syncthreads();
  }
  #pragma unroll
  for (int i = 0; i < 8; i++) spp[(ks * NB + bg * 8 + i) * DM2 + n] = acc[i];
}

// sum partials + bias, GLU, LN, write state into ring slot   (block per b)
__global__ __launch_bounds__(256) void kglu(const float* __restrict__ spp,
                                            const float* __restrict__ synb,
                                            const float* __restrict__ lng,
                                            const float* __restrict__ lnb,
                                            float* __restrict__ ring, int slot) {
  int b = blockIdx.x, t = threadIdx.x;
  __shared__ float srow[DM2];
  __shared__ float glu[DM];
  __shared__ float red[8];
  for (int n = t; n < DM2; n += 256) {
    float v = synb[n];
    #pragma unroll
    for (int ks = 0; ks < 4; ks++) v += spp[(ks * NB + b) * DM2 + n];
    srow[n] = v;
  }
  __syncthreads();
  float s = 0.f, sq = 0.f;
  for (int d = t; d < DM; d += 256) {
    float a = srow[d], g = srow[d + DM];
    float gl = a / (1.f + expf(-g));
    glu[d] = gl;
    s += gl; sq += gl * gl;
  }
  for (int o = 32; o; o >>= 1) { s += __shfl_xor(s, o); sq += __shfl_xor(sq, o); }
  if ((t & 63) == 0) { red[t >> 6] = s; red[4 + (t >> 6)] = sq; }
  __syncthreads();
  s = red[0] + red[1] + red[2] + red[3];
  sq = red[4] + red[5] + red[6] + red[7];
  float mean = s * (1.f / DM);
  float var = sq * (1.f / DM) - mean * mean;
  float rstd = rsqrtf(fmaxf(var, 0.f) + 1e-5f);
  for (int d = t; d < DM; d += 256) {
    float st = (glu[d] - mean) * rstd * lng[d] + lnb[d];
    ring[(slot * DM + d) * NB + b] = st;
  }
}

// per-neuron NLM: trace -> act   (block per d; lanes = jj)
__global__ __launch_bounds__(256) void knlm(const float* __restrict__ ring,
                                            const float* __restrict__ w1t,
                                            const float* __restrict__ b1,
                                            const float* __restrict__ w2t,
                                            const float* __restrict__ b2,
                                            float* __restrict__ act, int off) {
  int d = blockIdx.x, t = threadIdx.x;
  int jj = t & 63, bq = t >> 6;
  __shared__ float tr[NB * MEM];
  for (int e = t; e < NB * MEM; e += 256) {
    int m = e >> 5, b = e & 31;
    int slot = m + off; if (slot >= MEM) slot -= MEM;
    tr[b * MEM + m] = ring[(slot * DM + d) * NB + b];
  }
  float wA[MEM], wB[MEM];
  const float* wbase = w1t + (d * 128 + jj) * MEM;
  #pragma unroll
  for (int m = 0; m < MEM; m++) { wA[m] = wbase[m]; wB[m] = wbase[64 * MEM + m]; }
  float b1A = b1[d * 128 + jj], b1B = b1[d * 128 + jj + 64];
  float w20 = w2t[(d * 64 + jj) * 2], w21 = w2t[(d * 64 + jj) * 2 + 1];
  float b20 = b2[d * 2], b21 = b2[d * 2 + 1];
  __syncthreads();
  for (int b = bq * 8; b < bq * 8 + 8; b++) {
    float hA = b1A, hB = b1B;
    #pragma unroll
    for (int m = 0; m < MEM; m++) {
      float trv = tr[b * MEM + m];
      hA += trv * wA[m];
      hB += trv * wB[m];
    }
    float hg = hA / (1.f + expf(-hB));
    float p0 = hg * w20, p1 = hg * w21;
    for (int o = 32; o; o >>= 1) { p0 += __shfl_xor(p0, o); p1 += __shfl_xor(p1, o); }
    if (jj == 0) {
      float a0 = p0 + b20, a1 = p1 + b21;
      act[b * DM + d] = a0 / (1.f + expf(-a1));
    }
  }
}

// sync_o update + pred GEMM partials   (grid: 8 o-chunks x 4 k-splits x 2 b-halves)
__global__ __launch_bounds__(256) void kout1(const float* __restrict__ act,
                                             const float* __restrict__ dao_in, const float* __restrict__ dbo_in,
                                             float* __restrict__ dao_out, float* __restrict__ dbo_out,
                                             const float* __restrict__ ro,
                                             const int* __restrict__ iol, const int* __restrict__ ior,
                                             const float* __restrict__ outw,
                                             float* __restrict__ pp, float* __restrict__ outS, int last) {
  int oc = blockIdx.x, ks = blockIdx.y, bh = blockIdx.z, t = threadIdx.x;
  __shared__ float so[16 * 512];
  for (int e = t; e < 16 * 512; e += 256) {
    int bl = e >> 9, k = e & 511;
    int b = bh * 16 + bl;
    float dn = ro[k] * dao_in[b * NS + k] + act[b * DM + iol[k]] * act[b * DM + ior[k]];
    float bn = ro[k] * dbo_in[b * NS + k] + 1.f;
    float sv = dn / sqrtf(bn);
    so[bl * 512 + k] = sv;
    if (oc == 0 && ks == 0) {
      dao_out[b * NS + k] = dn;
      dbo_out[b * NS + k] = bn;
      if (last) outS[b * NS + k] = sv;
    }
  }
  __syncthreads();
  int o = oc * 128 + (t & 127);
  int bg = t >> 7;
  if (o < OD) {
    float acc[8] = {0.f};
    for (int k = ks * 128; k < ks * 128 + 128; k++) {
      float w = outw[k * OD + o];
      #pragma unroll
      for (int i = 0; i < 8; i++) acc[i] += so[(bg * 8 + i) * 512 + k] * w;
    }
    #pragma unroll
    for (int i = 0; i < 8; i++)
      pp[(ks * NB + bh * 16 + bg * 8 + i) * OD + o] = acc[i];
  }
}

// sum pred partials + bias, write predictions, entropy -> certainties   (block per b)
__global__ __launch_bounds__(256) void kout2(const float* __restrict__ pp,
                                             const float* __restrict__ outb,
                                             float* __restrict__ out, int it) {
  int b = blockIdx.x, t = threadIdx.x;
  __shared__ float pr[OD];
  __shared__ float red[12];
  for (int o = t; o < OD; o += 256) {
    float v = outb[o];
    #pragma unroll
    for (int ks = 0; ks < 4; ks++) v += pp[(ks * NB + b) * OD + o];
    pr[o] = v;
    out[(b * OD + o) * NITER + it] = v;
  }
  __syncthreads();
  float m = -1e30f;
  for (int o = t; o < OD; o += 256) m = fmaxf(m, pr[o]);
  for (int o = 32; o; o >>= 1) m = fmaxf(m, __shfl_xor(m, o));
  if ((t & 63) == 0) red[t >> 6] = m;
  __syncthreads();
  m = fmaxf(fmaxf(red[0], red[1]), fmaxf(red[2], red[3]));
  float s = 0.f, w = 0.f;
  for (int o = t; o < OD; o += 256) {
    float e = expf(pr[o] - m);
    s += e; w += e * pr[o];
  }
  for (int o = 32; o; o >>= 1) { s += __shfl_xor(s, o); w += __shfl_xor(w, o); }
  if ((t & 63) == 0) { red[4 + (t >> 6)] = s; red[8 + (t >> 6)] = w; }
  __syncthreads();
  if (t == 0) {
    s = red[4] + red[5] + red[6] + red[7];
    w = red[8] + red[9] + red[10] + red[11];
    float lse = m + logf(s);
    float ne = (lse - w / s) * (1.f / 6.907755278982137f);
    out[OFF_C + (b * 2) * NITER + it] = ne;
    out[OFF_C + (b * 2 + 1) * NITER + it] = 1.f - ne;
  }
}

// ---------------- host ----------------

extern "C" void kernel_launch(void* const* d_in, const int* in_sizes, int n_in,
                              void* d_out, int out_size, void* d_ws, size_t ws_size,
                              hipStream_t stream) {
  const float* x    = (const float*)d_in[0];
  const float* kvw  = (const float*)d_in[1];
  const float* kvb  = (const float*)d_in[2];
  const float* kvlg = (const float*)d_in[3];
  const float* kvlb = (const float*)d_in[4];
  const float* qw   = (const float*)d_in[5];
  const float* qb   = (const float*)d_in[6];
  const float* aw   = (const float*)d_in[7];
  const float* ab   = (const float*)d_in[8];
  const float* aow  = (const float*)d_in[9];
  const float* aob  = (const float*)d_in[10];
  const float* synw = (const float*)d_in[11];
  const float* synb = (const float*)d_in[12];
  const float* lng  = (const float*)d_in[13];
  const float* lnb  = (const float*)d_in[14];
  const float* tp1w = (const float*)d_in[15];
  const float* tp1b = (const float*)d_in[16];
  const float* tp2w = (const float*)d_in[17];
  const float* tp2b = (const float*)d_in[18];
  const float* sas  = (const float*)d_in[19];
  const float* strc = (const float*)d_in[20];
  const float* deca = (const float*)d_in[21];
  const float* deco = (const float*)d_in[22];
  const float* outw = (const float*)d_in[23];
  const float* outb = (const float*)d_in[24];
  const int* ial = (const int*)d_in[25];
  const int* iar = (const int*)d_in[26];
  const int* iol = (const int*)d_in[27];
  const int* ior = (const int*)d_in[28];
  float* out = (float*)d_out;
  float* ws = (float*)d_ws;

  // workspace layout (floats)
  float* kv      = ws;                 // 4,194,304
  float* Kb      = kv + 4194304;       // 4,194,304
  float* Vb      = Kb + 4194304;       // 4,194,304
  float* ring    = Vb + 4194304;       // 1,638,400
  float* act     = ring + 1638400;     // 65,536
  float* attnres = act + 65536;        // 16,384
  float* attn2   = attnres + 16384;    // 16,384
  float* qbuf    = attn2 + 16384;      // 16,384
  float* daa     = qbuf + 16384;       // 2*16,384
  float* dba     = daa + 32768;        // 2*16,384
  float* dao     = dba + 32768;        // 2*16,384
  float* dbo     = dao + 32768;        // 2*16,384
  float* ra      = dbo + 32768;        // 512
  float* ro      = ra + 512;           // 512
  float* spp     = ro + 512;           // 524,288
  float* w1t     = spp + 524288;       // 6,553,600
  float* w2t     = w1t + 6553600;      // 262,144
  float* pp      = w2t + 262144;       // 128,000

  kinit<<<6400, 256, 0, stream>>>(sas, strc, deca, deco, iol, ior,
                                  ring, act, daa, dba, dao, dbo, ra, ro);
  kkv<<<dim3(8, 16, 32), 256, 0, stream>>>(x, kvw, kvb, kv);
  kln<<<NB * S_LEN, 64, 0, stream>>>(kv, kvlg, kvlb);
  kkvproj<<<dim3(256, 8, 2), 256, 0, stream>>>(kv, aw, ab, Kb, Vb);
  ktr1<<<dim3(32, 16), 256, 0, stream>>>(tp1w, w1t);
  ktr2<<<32, 256, 0, stream>>>(tp2w, w2t);

  for (int it = 0; it < NITER; it++) {
    int p = it & 1;
    kq<<<NB, 256, 0, stream>>>(act, daa + p * 16384, dba + p * 16384,
                               daa + (p ^ 1) * 16384, dba + (p ^ 1) * 16384,
                               ra, ial, iar, qw, qb, aw, ab, qbuf);
    kattn<<<dim3(NH, NB), 256, 0, stream>>>(qbuf, Kb, Vb, attnres);
    kaout<<<NB, 256, 0, stream>>>(attnres, aow, aob, attn2);
    ksyn<<<dim3(64, 4), 256, 0, stream>>>(attn2, act, synw, spp);
    kglu<<<NB, 256, 0, stream>>>(spp, synb, lng, lnb, ring, it % MEM);
    knlm<<<DM, 256, 0, stream>>>(ring, w1t, tp1b, w2t, tp2b, act, (it + 1) % MEM);
    kout1<<<dim3(8, 4, 2), 256, 0, stream>>>(act, dao + p * 16384, dbo + p * 16384,
                                             dao + (p ^ 1) * 16384, dbo + (p ^ 1) * 16384,
                                             ro, iol, ior, outw, pp, out + OFF_S,
                                             (it == NITER - 1) ? 1 : 0);
    kout2<<<NB, 256, 0, stream>>>(pp, outb, out, it);
  }
}

// Round 3
// 5399.295 us; speedup vs baseline: 1.8889x; 1.8889x over previous
//
#include <hip/hip_runtime.h>
#include <hip/hip_bf16.h>

#define NB 32
#define S_LEN 256
#define NITER 25
#define DM 2048
#define DM2 4096
#define DI 512
#define NH 8
#define HD 64
#define NS 512
#define MEM 25
#define OD 1000

#define OFF_C 800000   // NB*OD*NITER
#define OFF_S 801600   // + NB*2*NITER

// ================= setup kernels =================

// kv[b,s,d] = sum_c x[b,c,s]*kvw[c,d] + kvb[d]; 8x8 register tile
__global__ __launch_bounds__(256) void kkv8(const float* __restrict__ x,
    const float* __restrict__ kvw, const float* __restrict__ kvb,
    float* __restrict__ kv) {
  __shared__ float xs[32][132];
  __shared__ float ws[32][132];
  int b = blockIdx.z, s0 = blockIdx.y * 128, d0 = blockIdx.x * 128;
  int t = threadIdx.x;
  int dg = t & 15, sg = t >> 4;
  float acc[8][8] = {};
  for (int c0 = 0; c0 < 512; c0 += 32) {
    for (int e = t; e < 4096; e += 256) {
      int cc = e >> 7, ss = e & 127;
      xs[cc][ss] = x[(b * 512 + c0 + cc) * 256 + s0 + ss];
      ws[cc][ss] = kvw[(c0 + cc) * 512 + d0 + ss];
    }
    __syncthreads();
    for (int cc = 0; cc < 32; cc++) {
      float av[8], bv[8];
      float4 a0 = *(const float4*)&xs[cc][sg * 8];
      float4 a1 = *(const float4*)&xs[cc][sg * 8 + 4];
      float4 b0 = *(const float4*)&ws[cc][dg * 8];
      float4 b1 = *(const float4*)&ws[cc][dg * 8 + 4];
      av[0]=a0.x; av[1]=a0.y; av[2]=a0.z; av[3]=a0.w;
      av[4]=a1.x; av[5]=a1.y; av[6]=a1.z; av[7]=a1.w;
      bv[0]=b0.x; bv[1]=b0.y; bv[2]=b0.z; bv[3]=b0.w;
      bv[4]=b1.x; bv[5]=b1.y; bv[6]=b1.z; bv[7]=b1.w;
      #pragma unroll
      for (int i = 0; i < 8; i++)
        #pragma unroll
        for (int j = 0; j < 8; j++) acc[i][j] += av[i] * bv[j];
    }
    __syncthreads();
  }
  float bias[8];
  #pragma unroll
  for (int j = 0; j < 8; j++) bias[j] = kvb[d0 + dg * 8 + j];
  #pragma unroll
  for (int i = 0; i < 8; i++) {
    int row = (b * 256 + s0 + sg * 8 + i) * 512 + d0 + dg * 8;
    #pragma unroll
    for (int j = 0; j < 8; j++) kv[row + j] = acc[i][j] + bias[j];
  }
}

// in-place LN over last dim (512)
__global__ __launch_bounds__(64) void kln(float* __restrict__ kv,
    const float* __restrict__ g, const float* __restrict__ bb) {
  int row = blockIdx.x;
  int lane = threadIdx.x;
  const int base = row * DI;
  float v[8], s = 0.f, sq = 0.f;
  #pragma unroll
  for (int i = 0; i < 8; i++) {
    v[i] = kv[base + lane + i * 64];
    s += v[i]; sq += v[i] * v[i];
  }
  for (int o = 32; o; o >>= 1) { s += __shfl_xor(s, o); sq += __shfl_xor(sq, o); }
  float mean = s * (1.f / DI);
  float var = sq * (1.f / DI) - mean * mean;
  float rstd = rsqrtf(fmaxf(var, 0.f) + 1e-5f);
  #pragma unroll
  for (int i = 0; i < 8; i++) {
    int d = lane + i * 64;
    kv[base + d] = (v[i] - mean) * rstd * g[d] + bb[d];
  }
}

// K/V projections, 8x8 register tile
__global__ __launch_bounds__(256) void kkvp8(const float* __restrict__ kv,
    const float* __restrict__ aw, const float* __restrict__ ab,
    float* __restrict__ Kb, float* __restrict__ Vb) {
  __shared__ float at[32][132];
  __shared__ float wt[32][132];
  int j0 = blockIdx.x * 128, r0 = blockIdx.y * 128, z = blockIdx.z;
  int woff = 512 * (1 + z);
  float* outp = z ? Vb : Kb;
  int t = threadIdx.x;
  int jg = t & 15, rg = t >> 4;
  float acc[8][8] = {};
  for (int m0 = 0; m0 < 512; m0 += 32) {
    for (int e = t; e < 4096; e += 256) {
      int hi = e >> 5, mm = e & 31;
      at[mm][hi] = kv[(r0 + hi) * 512 + m0 + mm];
      wt[mm][hi] = aw[(woff + j0 + hi) * 512 + m0 + mm];
    }
    __syncthreads();
    for (int mm = 0; mm < 32; mm++) {
      float av[8], bv[8];
      float4 a0 = *(const float4*)&at[mm][rg * 8];
      float4 a1 = *(const float4*)&at[mm][rg * 8 + 4];
      float4 b0 = *(const float4*)&wt[mm][jg * 8];
      float4 b1 = *(const float4*)&wt[mm][jg * 8 + 4];
      av[0]=a0.x; av[1]=a0.y; av[2]=a0.z; av[3]=a0.w;
      av[4]=a1.x; av[5]=a1.y; av[6]=a1.z; av[7]=a1.w;
      bv[0]=b0.x; bv[1]=b0.y; bv[2]=b0.z; bv[3]=b0.w;
      bv[4]=b1.x; bv[5]=b1.y; bv[6]=b1.z; bv[7]=b1.w;
      #pragma unroll
      for (int i = 0; i < 8; i++)
        #pragma unroll
        for (int j = 0; j < 8; j++) acc[i][j] += av[i] * bv[j];
    }
    __syncthreads();
  }
  float bias[8];
  #pragma unroll
  for (int j = 0; j < 8; j++) bias[j] = ab[woff + j0 + jg * 8 + j];
  #pragma unroll
  for (int i = 0; i < 8; i++) {
    int row = (r0 + rg * 8 + i) * 512 + j0 + jg * 8;
    #pragma unroll
    for (int j = 0; j < 8; j++) outp[row + j] = acc[i][j] + bias[j];
  }
}

// C[M][N] = sum_j A[j][*]·B[j][*]; both operands j-major. grid (N/128, M/128)
__global__ __launch_bounds__(256) void kgemmT(const float* __restrict__ A, int lda,
    const float* __restrict__ B, int ldb, float* __restrict__ C, int ldc, int J) {
  __shared__ float as[32][132];
  __shared__ float bs[32][132];
  int n0 = blockIdx.x * 128, m0 = blockIdx.y * 128;
  int t = threadIdx.x;
  int ng = t & 15, mg = t >> 4;
  float acc[8][8] = {};
  for (int j0 = 0; j0 < J; j0 += 32) {
    for (int e = t; e < 4096; e += 256) {
      int jj = e >> 7, uu = e & 127;
      as[jj][uu] = A[(j0 + jj) * lda + m0 + uu];
      bs[jj][uu] = B[(j0 + jj) * ldb + n0 + uu];
    }
    __syncthreads();
    for (int jj = 0; jj < 32; jj++) {
      float av[8], bv[8];
      float4 a0 = *(const float4*)&as[jj][mg * 8];
      float4 a1 = *(const float4*)&as[jj][mg * 8 + 4];
      float4 b0 = *(const float4*)&bs[jj][ng * 8];
      float4 b1 = *(const float4*)&bs[jj][ng * 8 + 4];
      av[0]=a0.x; av[1]=a0.y; av[2]=a0.z; av[3]=a0.w;
      av[4]=a1.x; av[5]=a1.y; av[6]=a1.z; av[7]=a1.w;
      bv[0]=b0.x; bv[1]=b0.y; bv[2]=b0.z; bv[3]=b0.w;
      bv[4]=b1.x; bv[5]=b1.y; bv[6]=b1.z; bv[7]=b1.w;
      #pragma unroll
      for (int i = 0; i < 8; i++)
        #pragma unroll
        for (int j = 0; j < 8; j++) acc[i][j] += av[i] * bv[j];
    }
    __syncthreads();
  }
  #pragma unroll
  for (int i = 0; i < 8; i++) {
    int row = (m0 + mg * 8 + i) * ldc + n0 + ng * 8;
    #pragma unroll
    for (int j = 0; j < 8; j++) C[row + j] = acc[i][j];
  }
}

// transpose RxC -> CxR (rows 0..R-1 of in)
__global__ __launch_bounds__(256) void ktrs(const float* __restrict__ in,
    float* __restrict__ outp, int R, int Cc) {
  __shared__ float tl[32][33];
  int c0 = blockIdx.x * 32, r0 = blockIdx.y * 32;
  int t = threadIdx.x;
  for (int e = t; e < 1024; e += 256) { int rr = e >> 5, cc = e & 31; tl[rr][cc] = in[(r0 + rr) * Cc + c0 + cc]; }
  __syncthreads();
  for (int e = t; e < 1024; e += 256) { int cc = e >> 5, rr = e & 31; outp[(c0 + cc) * R + r0 + rr] = tl[rr][cc]; }
}

// bc[n] = synb[n] + sum_j aob[j]*synw[j][n]
__global__ __launch_bounds__(256) void kbias(const float* __restrict__ synw,
    const float* __restrict__ aob, const float* __restrict__ synb,
    float* __restrict__ bc) {
  int n = blockIdx.x * 256 + threadIdx.x;
  float acc = synb[n];
  for (int j = 0; j < 512; j++) acc += aob[j] * synw[j * 4096 + n];
  bc[n] = acc;
}

// qbc[n] = ab[n] + sum_m qb[m]*aw[n][m]   (n<512 -> wq rows)
__global__ __launch_bounds__(256) void kqb(const float* __restrict__ aw,
    const float* __restrict__ ab, const float* __restrict__ qb,
    float* __restrict__ qbc) {
  int n = blockIdx.x * 256 + threadIdx.x;
  float acc = ab[n];
  for (int m = 0; m < 512; m++) acc += qb[m] * aw[n * 512 + m];
  qbc[n] = acc;
}

// tp1_w (25,128,2048) -> w1t[d][j][m]
__global__ __launch_bounds__(256) void ktr1(const float* __restrict__ w1, float* __restrict__ w1t) {
  __shared__ float tile[25][8][65];
  int d0 = blockIdx.x * 64, j0 = blockIdx.y * 8;
  int t = threadIdx.x;
  for (int e = t; e < 12800; e += 256) {
    int m = e >> 9;
    int rem = e & 511;
    int jj = rem >> 6, dd = rem & 63;
    tile[m][jj][dd] = w1[((m * 128) + j0 + jj) * DM + d0 + dd];
  }
  __syncthreads();
  for (int e = t; e < 12800; e += 256) {
    int dd = e / 200;
    int rem = e - dd * 200;
    int jj = rem / 25;
    int m = rem - jj * 25;
    w1t[(d0 + dd) * 3200 + (j0 + jj) * 25 + m] = tile[m][jj][dd];
  }
}

// tp2_w (64,2,2048) -> w2t[d][j*2+c]
__global__ __launch_bounds__(256) void ktr2(const float* __restrict__ w2, float* __restrict__ w2t) {
  __shared__ float tile[128][65];
  int d0 = blockIdx.x * 64;
  int t = threadIdx.x;
  for (int e = t; e < 8192; e += 256) {
    int row = e >> 6, dd = e & 63;
    tile[row][dd] = w2[row * DM + d0 + dd];
  }
  __syncthreads();
  for (int e = t; e < 8192; e += 256) {
    int dd = e >> 7, row = e & 127;
    w2t[(d0 + dd) * 128 + row] = tile[row][dd];
  }
}

// init dynamic state (runs AFTER setup GEMMs; lives in kv region)
__global__ __launch_bounds__(256) void kinit(const float* __restrict__ sas,
    const float* __restrict__ strc, const float* __restrict__ deca,
    const float* __restrict__ deco, const int* __restrict__ iol,
    const int* __restrict__ ior, const float* __restrict__ outb,
    float* __restrict__ ring, float* __restrict__ xcT,
    float* __restrict__ daaT, float* __restrict__ dbaT,
    float* __restrict__ daoT, float* __restrict__ dboT,
    float* __restrict__ ra, float* __restrict__ ro, float* __restrict__ predb) {
  int idx = blockIdx.x * 256 + threadIdx.x;
  int stride = gridDim.x * 256;
  for (int i = idx; i < MEM * NB * DM; i += stride) {
    int m = i >> 16;            // /(32*2048)
    int d = i & 2047;
    ring[i] = strc[d * MEM + m];
  }
  for (int i = idx; i < DM * NB; i += stride) {
    int d = i >> 5;
    xcT[(DI + d) * NB + (i & 31)] = sas[d];
  }
  for (int i = idx; i < NS * NB; i += stride) {
    int k = i >> 5;
    daaT[i] = 0.f; dbaT[i] = 0.f;
    daoT[i] = sas[iol[k]] * sas[ior[k]];
    dboT[i] = 1.f;
  }
  for (int i = idx; i < NS; i += stride) {
    ra[i] = __expf(-fminf(fmaxf(deca[i], 0.f), 15.f));
    ro[i] = __expf(-fminf(fmaxf(deco[i], 0.f), 15.f));
  }
  for (int i = idx; i < NB * OD; i += stride) {
    predb[i] = outb[i % OD];
  }
}

// ================= per-iteration kernels =================

// fused sync_a update + q = sa @ qwc (partials). grid (4 nc, 4 ks)
__global__ __launch_bounds__(256) void kq(const float* __restrict__ xcT,
    const float* __restrict__ daa_in, const float* __restrict__ dba_in,
    float* __restrict__ daa_out, float* __restrict__ dba_out,
    const float* __restrict__ ra, const int* __restrict__ ial,
    const int* __restrict__ iar, const float* __restrict__ qwc,
    float* __restrict__ qpart) {
  __shared__ float sx[128 * 32];
  int nc = blockIdx.x, ks = blockIdx.y;
  int k0 = ks * 128;
  int t = threadIdx.x;
  const float* actT = xcT + DI * NB;
  for (int e = t; e < 4096; e += 256) {
    int kk = e >> 5, b = e & 31;
    int k = k0 + kk;
    float dn = ra[k] * daa_in[k * 32 + b] + actT[ial[k] * 32 + b] * actT[iar[k] * 32 + b];
    float bn = ra[k] * dba_in[k * 32 + b] + 1.f;
    sx[e] = dn * rsqrtf(bn);
    if (nc == 0) { daa_out[k * 32 + b] = dn; dba_out[k * 32 + b] = bn; }
  }
  __syncthreads();
  int n = nc * 128 + (t & 127);
  int bh = t >> 7;
  float acc[16] = {};
  for (int kk = 0; kk < 128; kk++) {
    float w = qwc[(k0 + kk) * 512 + n];
    const float4* xp = (const float4*)&sx[kk * 32 + bh * 16];
    float4 x0 = xp[0], x1 = xp[1], x2 = xp[2], x3 = xp[3];
    float xv[16] = {x0.x,x0.y,x0.z,x0.w, x1.x,x1.y,x1.z,x1.w,
                    x2.x,x2.y,x2.z,x2.w, x3.x,x3.y,x3.z,x3.w};
    #pragma unroll
    for (int i = 0; i < 16; i++) acc[i] += xv[i] * w;
  }
  #pragma unroll
  for (int i = 0; i < 16; i++)
    qpart[(ks * 32 + bh * 16 + i) * 512 + n] = acc[i];
}

// attention per (h,b); writes attnres into xcT rows 0..511
__global__ __launch_bounds__(256) void kattn(const float* __restrict__ qpart,
    const float* __restrict__ qbc, const float* __restrict__ Kb,
    const float* __restrict__ Vb, float* __restrict__ xcT) {
  int h = blockIdx.x, b = blockIdx.y, t = threadIdx.x;
  __shared__ float qs[HD];
  __shared__ float sc[S_LEN];
  __shared__ float red[8];
  __shared__ float part[4][HD];
  if (t < HD) {
    int n = h * HD + t;
    float q = qbc[n];
    #pragma unroll
    for (int z = 0; z < 4; z++) q += qpart[(z * 32 + b) * DI + n];
    qs[t] = q;
  }
  __syncthreads();
  {
    const float* kr = Kb + (b * S_LEN + t) * DI + h * HD;
    float a = 0.f;
    #pragma unroll
    for (int d = 0; d < HD; d++) a += qs[d] * kr[d];
    sc[t] = a * 0.125f;
  }
  __syncthreads();
  float m = sc[t];
  for (int o = 32; o; o >>= 1) m = fmaxf(m, __shfl_xor(m, o));
  if ((t & 63) == 0) red[t >> 6] = m;
  __syncthreads();
  m = fmaxf(fmaxf(red[0], red[1]), fmaxf(red[2], red[3]));
  float p = __expf(sc[t] - m);
  float su = p;
  for (int o = 32; o; o >>= 1) su += __shfl_xor(su, o);
  if ((t & 63) == 0) red[4 + (t >> 6)] = su;
  sc[t] = p;
  __syncthreads();
  su = red[4] + red[5] + red[6] + red[7];
  {
    int d = t & 63, sg = t >> 6;
    const float* vb = Vb + b * S_LEN * DI + h * HD + d;
    float a = 0.f;
    for (int s = sg * 64; s < sg * 64 + 64; s++) a += sc[s] * vb[s * DI];
    part[sg][d] = a;
  }
  __syncthreads();
  if (t < HD)
    xcT[(h * HD + t) * NB + b] = (part[0][t] + part[1][t] + part[2][t] + part[3][t]) / su;
}

// syn partials: [attnres|act] @ [Wc|synw_bot]. grid (32 nc, 8 ks)
__global__ __launch_bounds__(256) void ksyn(const float* __restrict__ xcT,
    const float* __restrict__ Wc, const float* __restrict__ synw,
    float* __restrict__ spp) {
  __shared__ float xs[320 * 32];
  int nc = blockIdx.x, ks = blockIdx.y;
  int k0 = ks * 320;
  int t = threadIdx.x;
  for (int e = t; e < 320 * 32; e += 256) xs[e] = xcT[k0 * 32 + e];
  __syncthreads();
  int n = nc * 128 + (t & 127);
  int bh = t >> 7;
  float acc[16] = {};
  for (int kk = 0; kk < 320; kk++) {
    int k = k0 + kk;
    const float* wrow = (k < 512) ? (Wc + k * 4096) : (synw + k * 4096);
    float w = wrow[n];
    const float4* xp = (const float4*)&xs[kk * 32 + bh * 16];
    float4 x0 = xp[0], x1 = xp[1], x2 = xp[2], x3 = xp[3];
    float xv[16] = {x0.x,x0.y,x0.z,x0.w, x1.x,x1.y,x1.z,x1.w,
                    x2.x,x2.y,x2.z,x2.w, x3.x,x3.y,x3.z,x3.w};
    #pragma unroll
    for (int i = 0; i < 16; i++) acc[i] += xv[i] * w;
  }
  #pragma unroll
  for (int i = 0; i < 16; i++)
    spp[(ks * 32 + bh * 16 + i) * 4096 + n] = acc[i];
}

// sum partials + bias, GLU, LN -> ring slot. block per b
__global__ __launch_bounds__(256) void kglu(const float* __restrict__ spp,
    const float* __restrict__ bc, const float* __restrict__ lng,
    const float* __restrict__ lnb, float* __restrict__ ring, int slot) {
  int b = blockIdx.x, t = threadIdx.x;
  __shared__ float srow[4096];
  __shared__ float glu[2048];
  __shared__ float red[8];
  for (int n = t; n < 4096; n += 256) {
    float v = bc[n];
    #pragma unroll
    for (int ks = 0; ks < 8; ks++) v += spp[(ks * 32 + b) * 4096 + n];
    srow[n] = v;
  }
  __syncthreads();
  float s = 0.f, sq = 0.f;
  for (int d = t; d < 2048; d += 256) {
    float a = srow[d], g = srow[d + 2048];
    float gl = a / (1.f + __expf(-g));
    glu[d] = gl; s += gl; sq += gl * gl;
  }
  for (int o = 32; o; o >>= 1) { s += __shfl_xor(s, o); sq += __shfl_xor(sq, o); }
  if ((t & 63) == 0) { red[t >> 6] = s; red[4 + (t >> 6)] = sq; }
  __syncthreads();
  s = red[0] + red[1] + red[2] + red[3];
  sq = red[4] + red[5] + red[6] + red[7];
  float mean = s * (1.f / 2048.f);
  float var = sq * (1.f / 2048.f) - mean * mean;
  float rstd = rsqrtf(fmaxf(var, 0.f) + 1e-5f);
  for (int d = t; d < 2048; d += 256) {
    ring[(slot * 32 + b) * 2048 + d] = (glu[d] - mean) * rstd * lng[d] + lnb[d];
  }
}

// per-neuron NLM: trace(regs) -> act (xcT rows 512+). grid 256, thr = 8d x 32b
__global__ __launch_bounds__(256) void knlm(const float* __restrict__ ring,
    const float* __restrict__ w1t, const float* __restrict__ b1,
    const float* __restrict__ w2t, const float* __restrict__ b2,
    float* __restrict__ xcT, int off) {
  int d0 = blockIdx.x * 8;
  int t = threadIdx.x;
  int dd = t >> 5, b = t & 31;
  __shared__ float tr[8][25][32];
  for (int e = t; e < 800; e += 256) {
    int m = e >> 5, bb = e & 31;
    int slot = m + off; if (slot >= 25) slot -= 25;
    const float4* rp = (const float4*)&ring[(slot * 32 + bb) * 2048 + d0];
    float4 lo = rp[0], hi = rp[1];
    tr[0][m][bb] = lo.x; tr[1][m][bb] = lo.y; tr[2][m][bb] = lo.z; tr[3][m][bb] = lo.w;
    tr[4][m][bb] = hi.x; tr[5][m][bb] = hi.y; tr[6][m][bb] = hi.z; tr[7][m][bb] = hi.w;
  }
  __syncthreads();
  float trv[25];
  #pragma unroll
  for (int m = 0; m < 25; m++) trv[m] = tr[dd][m][b];
  int d = d0 + dd;
  const float* w1p = w1t + d * 3200;
  const float* b1p = b1 + d * 128;
  const float* w2p = w2t + d * 128;
  float p0 = 0.f, p1 = 0.f;
  for (int j = 0; j < 64; j++) {
    const float* wa = w1p + j * 25;
    const float* wb = w1p + (j + 64) * 25;
    float hA = b1p[j], hB = b1p[j + 64];
    #pragma unroll
    for (int m = 0; m < 25; m++) { hA += trv[m] * wa[m]; hB += trv[m] * wb[m]; }
    float hg = hA / (1.f + __expf(-hB));
    p0 += hg * w2p[2 * j]; p1 += hg * w2p[2 * j + 1];
  }
  float a0 = p0 + b2[2 * d], a1 = p1 + b2[2 * d + 1];
  xcT[(DI + d) * NB + b] = a0 / (1.f + __expf(-a1));
}

// fused sync_o update + pred partials (atomic into predb). grid (8 oc, 4 ks)
__global__ __launch_bounds__(256) void kout(const float* __restrict__ xcT,
    const float* __restrict__ dao_in, const float* __restrict__ dbo_in,
    float* __restrict__ dao_out, float* __restrict__ dbo_out,
    const float* __restrict__ ro, const int* __restrict__ iol,
    const int* __restrict__ ior, const float* __restrict__ outw,
    float* __restrict__ predb, float* __restrict__ outS, int last) {
  __shared__ float so[128 * 32];
  int oc = blockIdx.x, ks = blockIdx.y;
  int k0 = ks * 128;
  int t = threadIdx.x;
  const float* actT = xcT + DI * NB;
  for (int e = t; e < 4096; e += 256) {
    int kk = e >> 5, b = e & 31;
    int k = k0 + kk;
    float dn = ro[k] * dao_in[k * 32 + b] + actT[iol[k] * 32 + b] * actT[ior[k] * 32 + b];
    float bn = ro[k] * dbo_in[k * 32 + b] + 1.f;
    float sv = dn * rsqrtf(bn);
    so[e] = sv;
    if (oc == 0) {
      dao_out[k * 32 + b] = dn; dbo_out[k * 32 + b] = bn;
      if (last) outS[b * 512 + k] = sv;
    }
  }
  __syncthreads();
  int o = oc * 128 + (t & 127);
  int bh = t >> 7;
  int oe = (o < OD) ? o : (OD - 1);
  float acc[16] = {};
  for (int kk = 0; kk < 128; kk++) {
    float w = outw[(k0 + kk) * OD + oe];
    const float4* xp = (const float4*)&so[kk * 32 + bh * 16];
    float4 x0 = xp[0], x1 = xp[1], x2 = xp[2], x3 = xp[3];
    float xv[16] = {x0.x,x0.y,x0.z,x0.w, x1.x,x1.y,x1.z,x1.w,
                    x2.x,x2.y,x2.z,x2.w, x3.x,x3.y,x3.z,x3.w};
    #pragma unroll
    for (int i = 0; i < 16; i++) acc[i] += xv[i] * w;
  }
  if (o < OD) {
    #pragma unroll
    for (int i = 0; i < 16; i++)
      atomicAdd(&predb[(bh * 16 + i) * OD + o], acc[i]);
  }
}

// read predb -> predictions + entropy/certainty; re-init predb for next iter
__global__ __launch_bounds__(256) void kout2(float* __restrict__ predb,
    const float* __restrict__ outb, float* __restrict__ out, int it) {
  int b = blockIdx.x, t = threadIdx.x;
  __shared__ float pr[OD];
  __shared__ float red[12];
  for (int o = t; o < OD; o += 256) {
    float v = predb[b * OD + o];
    pr[o] = v;
    out[(b * OD + o) * NITER + it] = v;
  }
  __syncthreads();
  for (int o = t; o < OD; o += 256) predb[b * OD + o] = outb[o];
  float m = -1e30f;
  for (int o = t; o < OD; o += 256) m = fmaxf(m, pr[o]);
  for (int o = 32; o; o >>= 1) m = fmaxf(m, __shfl_xor(m, o));
  if ((t & 63) == 0) red[t >> 6] = m;
  __syncthreads();
  m = fmaxf(fmaxf(red[0], red[1]), fmaxf(red[2], red[3]));
  float s = 0.f, w = 0.f;
  for (int o = t; o < OD; o += 256) {
    float e = __expf(pr[o] - m);
    s += e; w += e * pr[o];
  }
  for (int o = 32; o; o >>= 1) { s += __shfl_xor(s, o); w += __shfl_xor(w, o); }
  if ((t & 63) == 0) { red[4 + (t >> 6)] = s; red[8 + (t >> 6)] = w; }
  __syncthreads();
  if (t == 0) {
    s = red[4] + red[5] + red[6] + red[7];
    w = red[8] + red[9] + red[10] + red[11];
    float lse = m + __logf(s);
    float ne = (lse - w / s) * (1.f / 6.907755278982137f);
    out[OFF_C + (b * 2) * NITER + it] = ne;
    out[OFF_C + (b * 2 + 1) * NITER + it] = 1.f - ne;
  }
}

// ================= host =================

extern "C" void kernel_launch(void* const* d_in, const int* in_sizes, int n_in,
                              void* d_out, int out_size, void* d_ws, size_t ws_size,
                              hipStream_t stream) {
  const float* x    = (const float*)d_in[0];
  const float* kvw  = (const float*)d_in[1];
  const float* kvb  = (const float*)d_in[2];
  const float* kvlg = (const float*)d_in[3];
  const float* kvlb = (const float*)d_in[4];
  const float* qw   = (const float*)d_in[5];
  const float* qb   = (const float*)d_in[6];
  const float* aw   = (const float*)d_in[7];
  const float* ab   = (const float*)d_in[8];
  const float* aow  = (const float*)d_in[9];
  const float* aob  = (const float*)d_in[10];
  const float* synw = (const float*)d_in[11];
  const float* synb = (const float*)d_in[12];
  const float* lng  = (const float*)d_in[13];
  const float* lnb  = (const float*)d_in[14];
  const float* tp1w = (const float*)d_in[15];
  const float* tp1b = (const float*)d_in[16];
  const float* tp2w = (const float*)d_in[17];
  const float* tp2b = (const float*)d_in[18];
  const float* sas  = (const float*)d_in[19];
  const float* strc = (const float*)d_in[20];
  const float* deca = (const float*)d_in[21];
  const float* deco = (const float*)d_in[22];
  const float* outw = (const float*)d_in[23];
  const float* outb = (const float*)d_in[24];
  const int* ial = (const int*)d_in[25];
  const int* iar = (const int*)d_in[26];
  const int* iol = (const int*)d_in[27];
  const int* ior = (const int*)d_in[28];
  float* out = (float*)d_out;
  float* ws = (float*)d_ws;

  // persistent regions
  float* kvreg = ws;                    // 4,194,304 (setup: kv matrix; loop: scratch below)
  float* Kb    = ws + 4194304;          // 4,194,304
  float* Vb    = Kb + 4194304;          // 4,194,304
  float* w1t   = Vb + 4194304;          // 6,553,600
  float* Wc    = w1t + 6553600;         // 2,097,152
  // total 21,233,664 floats = 84.9 MB

  // kv region internals (valid only after kkvp8)
  float* ring  = kvreg;                 // 1,638,400
  float* xcT   = ring + 1638400;        // 81,920   (rows 0..511 attnres, 512.. act)
  float* spp   = xcT + 81920;           // 1,048,576
  float* qpart = spp + 1048576;         // 65,536
  float* predb = qpart + 65536;         // 32,000
  float* daaT  = predb + 32000;         // 32,768 (2 halves)
  float* dbaT  = daaT + 32768;          // 32,768
  float* daoT  = dbaT + 32768;          // 32,768
  float* dboT  = daoT + 32768;          // 32,768
  float* ra    = dboT + 32768;          // 512
  float* ro    = ra + 512;              // 512
  float* w2t   = ro + 512;              // 262,144
  float* qwc   = w2t + 262144;          // 262,144
  float* qbc   = qwc + 262144;          // 512
  float* bc    = qbc + 512;             // 4,096
  // setup-only temps aliased over spp
  float* qwT   = spp;                   // 262,144
  float* awT   = spp + 262144;          // 262,144
  float* kv    = kvreg;                 // full region during setup

  // ---- setup ----
  kkv8<<<dim3(4, 2, 32), 256, 0, stream>>>(x, kvw, kvb, kv);
  kln<<<NB * S_LEN, 64, 0, stream>>>(kv, kvlg, kvlb);
  kkvp8<<<dim3(4, 64, 2), 256, 0, stream>>>(kv, aw, ab, Kb, Vb);
  // kv dead; build folded weights
  ktrs<<<dim3(16, 16), 256, 0, stream>>>(qw, qwT, 512, 512);
  ktrs<<<dim3(16, 16), 256, 0, stream>>>(aw, awT, 512, 512);      // wq rows
  kgemmT<<<dim3(4, 4), 256, 0, stream>>>(qwT, 512, awT, 512, qwc, 512, 512);
  kgemmT<<<dim3(32, 4), 256, 0, stream>>>(aow, 512, synw, 4096, Wc, 4096, 512);
  kqb<<<2, 256, 0, stream>>>(aw, ab, qb, qbc);
  kbias<<<16, 256, 0, stream>>>(synw, aob, synb, bc);
  ktr1<<<dim3(32, 16), 256, 0, stream>>>(tp1w, w1t);
  ktr2<<<32, 256, 0, stream>>>(tp2w, w2t);
  kinit<<<6400, 256, 0, stream>>>(sas, strc, deca, deco, iol, ior, outb,
                                  ring, xcT, daaT, dbaT, daoT, dboT, ra, ro, predb);

  // ---- iterations ----
  for (int it = 0; it < NITER; it++) {
    int p = it & 1;
    kq<<<dim3(4, 4), 256, 0, stream>>>(xcT, daaT + p * 16384, dbaT + p * 16384,
                                       daaT + (p ^ 1) * 16384, dbaT + (p ^ 1) * 16384,
                                       ra, ial, iar, qwc, qpart);
    kattn<<<dim3(NH, NB), 256, 0, stream>>>(qpart, qbc, Kb, Vb, xcT);
    ksyn<<<dim3(32, 8), 256, 0, stream>>>(xcT, Wc, synw, spp);
    kglu<<<NB, 256, 0, stream>>>(spp, bc, lng, lnb, ring, it % MEM);
    knlm<<<256, 256, 0, stream>>>(ring, w1t, tp1b, w2t, tp2b, xcT, (it + 1) % MEM);
    kout<<<dim3(8, 4), 256, 0, stream>>>(xcT, daoT + p * 16384, dboT + p * 16384,
                                         daoT + (p ^ 1) * 16384, dboT + (p ^ 1) * 16384,
                                         ro, iol, ior, outw, predb, out + OFF_S,
                                         (it == NITER - 1) ? 1 : 0);
    kout2<<<NB, 256, 0, stream>>>(predb, outb, out, it);
  }
}

// Round 4
// 3173.678 us; speedup vs baseline: 3.2136x; 1.7013x over previous
//
#include <hip/hip_runtime.h>
#include <hip/hip_bf16.h>
#include <hip/hip_fp16.h>

#define NB 32
#define S_LEN 256
#define NITER 25
#define DM 2048
#define DM2 4096
#define DI 512
#define NH 8
#define HD 64
#define NS 512
#define MEM 25
#define OD 1000

#define OFF_C 800000   // NB*OD*NITER
#define OFF_S 801600   // + NB*2*NITER

typedef _Float16 h8 __attribute__((ext_vector_type(8)));
typedef float f4 __attribute__((ext_vector_type(4)));

__device__ __forceinline__ uint packh2(float a, float b) {
  return ((uint)__half_as_ushort(__float2half_rn(b)) << 16) |
         (uint)__half_as_ushort(__float2half_rn(a));
}

// ================= setup kernels =================

// kv[b,s,d] = sum_c x[b,c,s]*kvw[c,d] + kvb[d]; 8x8 tile, conflict-free cols
__global__ __launch_bounds__(256) void kkv8(const float* __restrict__ x,
    const float* __restrict__ kvw, const float* __restrict__ kvb,
    float* __restrict__ kv) {
  __shared__ float xs[32][132];
  __shared__ float ws[32][132];
  int b = blockIdx.z, s0 = blockIdx.y * 128, d0 = blockIdx.x * 128;
  int t = threadIdx.x;
  int dg = t & 15, sg = t >> 4;
  float acc[8][8] = {};
  for (int c0 = 0; c0 < 512; c0 += 32) {
    for (int e = t; e < 4096; e += 256) {
      int cc = e >> 7, ss = e & 127;
      xs[cc][ss] = x[(b * 512 + c0 + cc) * 256 + s0 + ss];
      ws[cc][ss] = kvw[(c0 + cc) * 512 + d0 + ss];
    }
    __syncthreads();
    for (int cc = 0; cc < 32; cc++) {
      float av[8], bv[8];
      float4 a0 = *(const float4*)&xs[cc][sg * 8];
      float4 a1 = *(const float4*)&xs[cc][sg * 8 + 4];
      float4 b0 = *(const float4*)&ws[cc][dg * 4];        // cols dg*4..+3
      float4 b1 = *(const float4*)&ws[cc][64 + dg * 4];   // cols 64+dg*4..+3
      av[0]=a0.x; av[1]=a0.y; av[2]=a0.z; av[3]=a0.w;
      av[4]=a1.x; av[5]=a1.y; av[6]=a1.z; av[7]=a1.w;
      bv[0]=b0.x; bv[1]=b0.y; bv[2]=b0.z; bv[3]=b0.w;
      bv[4]=b1.x; bv[5]=b1.y; bv[6]=b1.z; bv[7]=b1.w;
      #pragma unroll
      for (int i = 0; i < 8; i++)
        #pragma unroll
        for (int j = 0; j < 8; j++) acc[i][j] += av[i] * bv[j];
    }
    __syncthreads();
  }
  float bias[8];
  #pragma unroll
  for (int j = 0; j < 4; j++) { bias[j] = kvb[d0 + dg * 4 + j]; bias[4 + j] = kvb[d0 + 64 + dg * 4 + j]; }
  #pragma unroll
  for (int i = 0; i < 8; i++) {
    int row = (b * 256 + s0 + sg * 8 + i) * 512 + d0;
    float4 s0v = { acc[i][0] + bias[0], acc[i][1] + bias[1], acc[i][2] + bias[2], acc[i][3] + bias[3] };
    float4 s1v = { acc[i][4] + bias[4], acc[i][5] + bias[5], acc[i][6] + bias[6], acc[i][7] + bias[7] };
    *(float4*)&kv[row + dg * 4] = s0v;
    *(float4*)&kv[row + 64 + dg * 4] = s1v;
  }
}

// in-place LN over last dim (512)
__global__ __launch_bounds__(64) void kln(float* __restrict__ kv,
    const float* __restrict__ g, const float* __restrict__ bb) {
  int row = blockIdx.x;
  int lane = threadIdx.x;
  const int base = row * DI;
  float v[8], s = 0.f, sq = 0.f;
  #pragma unroll
  for (int i = 0; i < 8; i++) {
    v[i] = kv[base + lane + i * 64];
    s += v[i]; sq += v[i] * v[i];
  }
  for (int o = 32; o; o >>= 1) { s += __shfl_xor(s, o); sq += __shfl_xor(sq, o); }
  float mean = s * (1.f / DI);
  float var = sq * (1.f / DI) - mean * mean;
  float rstd = rsqrtf(fmaxf(var, 0.f) + 1e-5f);
  #pragma unroll
  for (int i = 0; i < 8; i++) {
    int d = lane + i * 64;
    kv[base + d] = (v[i] - mean) * rstd * g[d] + bb[d];
  }
}

// K/V projections -> fp16, conflict-free cols
__global__ __launch_bounds__(256) void kkvp16(const float* __restrict__ kv,
    const float* __restrict__ aw, const float* __restrict__ ab,
    __half* __restrict__ Kb, __half* __restrict__ Vb) {
  __shared__ float at[32][132];
  __shared__ float wt[32][132];
  int j0 = blockIdx.x * 128, r0 = blockIdx.y * 128, z = blockIdx.z;
  int woff = 512 * (1 + z);
  __half* outp = z ? Vb : Kb;
  int t = threadIdx.x;
  int jg = t & 15, rg = t >> 4;
  float acc[8][8] = {};
  for (int m0 = 0; m0 < 512; m0 += 32) {
    for (int e = t; e < 4096; e += 256) {
      int hi = e >> 5, mm = e & 31;
      at[mm][hi] = kv[(r0 + hi) * 512 + m0 + mm];
      wt[mm][hi] = aw[(woff + j0 + hi) * 512 + m0 + mm];
    }
    __syncthreads();
    for (int mm = 0; mm < 32; mm++) {
      float av[8], bv[8];
      float4 a0 = *(const float4*)&at[mm][rg * 8];
      float4 a1 = *(const float4*)&at[mm][rg * 8 + 4];
      float4 b0 = *(const float4*)&wt[mm][jg * 4];
      float4 b1 = *(const float4*)&wt[mm][64 + jg * 4];
      av[0]=a0.x; av[1]=a0.y; av[2]=a0.z; av[3]=a0.w;
      av[4]=a1.x; av[5]=a1.y; av[6]=a1.z; av[7]=a1.w;
      bv[0]=b0.x; bv[1]=b0.y; bv[2]=b0.z; bv[3]=b0.w;
      bv[4]=b1.x; bv[5]=b1.y; bv[6]=b1.z; bv[7]=b1.w;
      #pragma unroll
      for (int i = 0; i < 8; i++)
        #pragma unroll
        for (int j = 0; j < 8; j++) acc[i][j] += av[i] * bv[j];
    }
    __syncthreads();
  }
  float bias[8];
  #pragma unroll
  for (int j = 0; j < 4; j++) { bias[j] = ab[woff + j0 + jg * 4 + j]; bias[4 + j] = ab[woff + j0 + 64 + jg * 4 + j]; }
  #pragma unroll
  for (int i = 0; i < 8; i++) {
    int row = (r0 + rg * 8 + i) * 512 + j0;
    #pragma unroll
    for (int j = 0; j < 4; j++) {
      outp[row + jg * 4 + j] = __float2half_rn(acc[i][j] + bias[j]);
      outp[row + 64 + jg * 4 + j] = __float2half_rn(acc[i][4 + j] + bias[4 + j]);
    }
  }
}

// C[M][N] = sum_j A[j][*]·B[j][*]; grid (N/128, M/128), conflict-free cols
__global__ __launch_bounds__(256) void kgemmT(const float* __restrict__ A, int lda,
    const float* __restrict__ B, int ldb, float* __restrict__ C, int ldc, int J) {
  __shared__ float as[32][132];
  __shared__ float bs[32][132];
  int n0 = blockIdx.x * 128, m0 = blockIdx.y * 128;
  int t = threadIdx.x;
  int ng = t & 15, mg = t >> 4;
  float acc[8][8] = {};
  for (int j0 = 0; j0 < J; j0 += 32) {
    for (int e = t; e < 4096; e += 256) {
      int jj = e >> 7, uu = e & 127;
      as[jj][uu] = A[(j0 + jj) * lda + m0 + uu];
      bs[jj][uu] = B[(j0 + jj) * ldb + n0 + uu];
    }
    __syncthreads();
    for (int jj = 0; jj < 32; jj++) {
      float av[8], bv[8];
      float4 a0 = *(const float4*)&as[jj][mg * 8];
      float4 a1 = *(const float4*)&as[jj][mg * 8 + 4];
      float4 b0 = *(const float4*)&bs[jj][ng * 4];
      float4 b1 = *(const float4*)&bs[jj][64 + ng * 4];
      av[0]=a0.x; av[1]=a0.y; av[2]=a0.z; av[3]=a0.w;
      av[4]=a1.x; av[5]=a1.y; av[6]=a1.z; av[7]=a1.w;
      bv[0]=b0.x; bv[1]=b0.y; bv[2]=b0.z; bv[3]=b0.w;
      bv[4]=b1.x; bv[5]=b1.y; bv[6]=b1.z; bv[7]=b1.w;
      #pragma unroll
      for (int i = 0; i < 8; i++)
        #pragma unroll
        for (int j = 0; j < 8; j++) acc[i][j] += av[i] * bv[j];
    }
    __syncthreads();
  }
  #pragma unroll
  for (int i = 0; i < 8; i++) {
    int row = (m0 + mg * 8 + i) * ldc + n0;
    float4 s0v = { acc[i][0], acc[i][1], acc[i][2], acc[i][3] };
    float4 s1v = { acc[i][4], acc[i][5], acc[i][6], acc[i][7] };
    *(float4*)&C[row + ng * 4] = s0v;
    *(float4*)&C[row + 64 + ng * 4] = s1v;
  }
}

// transpose RxC -> CxR
__global__ __launch_bounds__(256) void ktrs(const float* __restrict__ in,
    float* __restrict__ outp, int R, int Cc) {
  __shared__ float tl[32][33];
  int c0 = blockIdx.x * 32, r0 = blockIdx.y * 32;
  int t = threadIdx.x;
  for (int e = t; e < 1024; e += 256) { int rr = e >> 5, cc = e & 31; tl[rr][cc] = in[(r0 + rr) * Cc + c0 + cc]; }
  __syncthreads();
  for (int e = t; e < 1024; e += 256) { int cc = e >> 5, rr = e & 31; outp[(c0 + cc) * R + r0 + rr] = tl[rr][cc]; }
}

// elementwise fp32 -> fp16
__global__ __launch_bounds__(256) void kcast16(const float* __restrict__ in,
    ushort* __restrict__ outp, int n) {
  for (int i = blockIdx.x * 256 + threadIdx.x; i < n; i += gridDim.x * 256)
    outp[i] = __half_as_ushort(__float2half_rn(in[i]));
}

// synwT16[n][k] (k<512: from WcT[n][k]; else transpose-cast synw[k][n])
__global__ __launch_bounds__(256) void kpackS(const float* __restrict__ WcT,
    const float* __restrict__ synw, ushort* __restrict__ outp) {
  int k0 = blockIdx.x * 32, n0 = blockIdx.y * 32;
  int t = threadIdx.x;
  if (k0 < 512) {
    for (int e = t; e < 1024; e += 256) {
      int cc = e >> 5, rr = e & 31;
      outp[(n0 + cc) * 2560 + k0 + rr] = __half_as_ushort(__float2half_rn(WcT[(n0 + cc) * 512 + k0 + rr]));
    }
  } else {
    __shared__ float tl[32][33];
    for (int e = t; e < 1024; e += 256) { int rr = e >> 5, cc = e & 31; tl[rr][cc] = synw[(k0 + rr) * 4096 + n0 + cc]; }
    __syncthreads();
    for (int e = t; e < 1024; e += 256) {
      int cc = e >> 5, rr = e & 31;
      outp[(n0 + cc) * 2560 + k0 + rr] = __half_as_ushort(__float2half_rn(tl[rr][cc]));
    }
  }
}

// outwT16[o(1024 pad)][k(512)] from outw[k][1000]
__global__ __launch_bounds__(256) void koutw(const float* __restrict__ outw,
    ushort* __restrict__ outp) {
  __shared__ float tl[32][33];
  int k0 = blockIdx.x * 32, o0 = blockIdx.y * 32;
  int t = threadIdx.x;
  for (int e = t; e < 1024; e += 256) {
    int rr = e >> 5, cc = e & 31;
    tl[rr][cc] = (o0 + cc < OD) ? outw[(k0 + rr) * OD + o0 + cc] : 0.f;
  }
  __syncthreads();
  for (int e = t; e < 1024; e += 256) {
    int cc = e >> 5, rr = e & 31;
    outp[(o0 + cc) * 512 + k0 + rr] = __half_as_ushort(__float2half_rn(tl[rr][cc]));
  }
}

// bc[n] = synb[n] + sum_j aob[j]*synw[j][n]
__global__ __launch_bounds__(256) void kbias(const float* __restrict__ synw,
    const float* __restrict__ aob, const float* __restrict__ synb,
    float* __restrict__ bc) {
  int n = blockIdx.x * 256 + threadIdx.x;
  float acc = synb[n];
  for (int j = 0; j < 512; j++) acc += aob[j] * synw[j * 4096 + n];
  bc[n] = acc;
}

// qbc[n] = ab[n] + sum_m qb[m]*aw[n][m]
__global__ __launch_bounds__(256) void kqb(const float* __restrict__ aw,
    const float* __restrict__ ab, const float* __restrict__ qb,
    float* __restrict__ qbc) {
  int n = blockIdx.x * 256 + threadIdx.x;
  float acc = ab[n];
  for (int m = 0; m < 512; m++) acc += qb[m] * aw[n * 512 + m];
  qbc[n] = acc;
}

// w1n[m][d][j] packed half2(A,B), m<25, from tp1w (25,128,2048)
__global__ __launch_bounds__(256) void kpack1(const float* __restrict__ w1,
    uint* __restrict__ w1n) {
  __shared__ float tA[16][65];
  __shared__ float tB[16][65];
  int d0 = blockIdx.x * 64, j0 = blockIdx.y * 16;
  int t = threadIdx.x;
  for (int m = 0; m < 25; m++) {
    for (int e = t; e < 1024; e += 256) {
      int jr = e >> 6, dd = e & 63;
      tA[jr][dd] = w1[(m * 128 + j0 + jr) * DM + d0 + dd];
      tB[jr][dd] = w1[(m * 128 + 64 + j0 + jr) * DM + d0 + dd];
    }
    __syncthreads();
    for (int e = t; e < 1024; e += 256) {
      int dd = e >> 4, jr = e & 15;
      w1n[m * 131072 + (d0 + dd) * 64 + j0 + jr] = packh2(tA[jr][dd], tB[jr][dd]);
    }
    __syncthreads();
  }
}

// bias row m=25 of w1n from tp1b (2048,128)
__global__ __launch_bounds__(256) void kpackB(const float* __restrict__ b1,
    uint* __restrict__ w1n) {
  int i = blockIdx.x * 256 + threadIdx.x;   // 131072
  int d = i >> 6, j = i & 63;
  w1n[25 * 131072 + i] = packh2(b1[d * 128 + j], b1[d * 128 + 64 + j]);
}

// tp2_w (64,2,2048) -> w2t[d][j*2+c] fp32
__global__ __launch_bounds__(256) void ktr2(const float* __restrict__ w2, float* __restrict__ w2t) {
  __shared__ float tile[128][65];
  int d0 = blockIdx.x * 64;
  int t = threadIdx.x;
  for (int e = t; e < 8192; e += 256) {
    int row = e >> 6, dd = e & 63;
    tile[row][dd] = w2[row * DM + d0 + dd];
  }
  __syncthreads();
  for (int e = t; e < 8192; e += 256) {
    int dd = e >> 7, row = e & 127;
    w2t[(d0 + dd) * 128 + row] = tile[row][dd];
  }
}

// init dynamic state
__global__ __launch_bounds__(256) void kinit(const float* __restrict__ sas,
    const float* __restrict__ strc, const float* __restrict__ deca,
    const float* __restrict__ deco, const int* __restrict__ iol,
    const int* __restrict__ ior, const float* __restrict__ outb,
    float* __restrict__ ring, float* __restrict__ xcT,
    float* __restrict__ daaT, float* __restrict__ dbaT,
    float* __restrict__ daoT, float* __restrict__ dboT,
    float* __restrict__ ra, float* __restrict__ ro, float* __restrict__ predb) {
  int idx = blockIdx.x * 256 + threadIdx.x;
  int stride = gridDim.x * 256;
  for (int i = idx; i < MEM * NB * DM; i += stride) {
    int m = i >> 16;
    int d = i & 2047;
    ring[i] = strc[d * MEM + m];
  }
  for (int i = idx; i < DM * NB; i += stride) {
    int d = i >> 5;
    xcT[(DI + d) * NB + (i & 31)] = sas[d];
  }
  for (int i = idx; i < NS * NB; i += stride) {
    int k = i >> 5;
    daaT[i] = 0.f; dbaT[i] = 0.f;
    daoT[i] = sas[iol[k]] * sas[ior[k]];
    dboT[i] = 1.f;
  }
  for (int i = idx; i < NS; i += stride) {
    ra[i] = __expf(-fminf(fmaxf(deca[i], 0.f), 15.f));
    ro[i] = __expf(-fminf(fmaxf(deco[i], 0.f), 15.f));
  }
  for (int i = idx; i < NB * 1024; i += stride) {
    int o = i & 1023;
    predb[i] = (o < OD) ? outb[o] : 0.f;
  }
}

// ================= per-iteration kernels =================

// fused sync_a update + q partials via MFMA. grid (4 nc, 4 ks)
__global__ __launch_bounds__(256) void kq(const float* __restrict__ xcT,
    const float* __restrict__ daa_in, const float* __restrict__ dba_in,
    float* __restrict__ daa_out, float* __restrict__ dba_out,
    const float* __restrict__ ra, const int* __restrict__ ial,
    const int* __restrict__ iar, const ushort* __restrict__ Wt,
    float* __restrict__ qpart) {
  __shared__ float sx[128 * 32];
  __shared__ __align__(16) _Float16 a16[32 * 136];
  __shared__ __align__(16) _Float16 w16[128 * 136];
  int nc = blockIdx.x, ks = blockIdx.y;
  int k0 = ks * 128, n0 = nc * 128;
  int t = threadIdx.x;
  const float* actT = xcT + DI * NB;
  for (int e = t; e < 4096; e += 256) {
    int kk = e >> 5, b = e & 31;
    int k = k0 + kk;
    float dn = ra[k] * daa_in[k * 32 + b] + actT[ial[k] * 32 + b] * actT[iar[k] * 32 + b];
    float bn = ra[k] * dba_in[k * 32 + b] + 1.f;
    sx[e] = dn * rsqrtf(bn);
    if (nc == 0) { daa_out[k * 32 + b] = dn; dba_out[k * 32 + b] = bn; }
  }
  {
    int row = t >> 1, hh = (t & 1) * 64;
    const uint4* g = reinterpret_cast<const uint4*>(Wt + (n0 + row) * 512 + k0 + hh);
    uint4* ld = reinterpret_cast<uint4*>(&w16[row * 136 + hh]);
    #pragma unroll
    for (int u = 0; u < 8; u++) ld[u] = g[u];
  }
  __syncthreads();
  for (int e = t; e < 4096; e += 256) {
    int kk = e >> 5, b = e & 31;
    a16[b * 136 + kk] = (_Float16)sx[kk * 32 + b];
  }
  __syncthreads();
  int l = t & 63, w = t >> 6;
  int nsub = w * 32;
  int lr = l & 15, lg = l >> 4;
  f4 acc[2][2] = {};
  #pragma unroll
  for (int s = 0; s < 4; s++) {
    h8 af0 = *(const h8*)&a16[lr * 136 + s * 32 + lg * 8];
    h8 af1 = *(const h8*)&a16[(16 + lr) * 136 + s * 32 + lg * 8];
    h8 bf0 = *(const h8*)&w16[(nsub + lr) * 136 + s * 32 + lg * 8];
    h8 bf1 = *(const h8*)&w16[(nsub + 16 + lr) * 136 + s * 32 + lg * 8];
    acc[0][0] = __builtin_amdgcn_mfma_f32_16x16x32_f16(af0, bf0, acc[0][0], 0, 0, 0);
    acc[0][1] = __builtin_amdgcn_mfma_f32_16x16x32_f16(af0, bf1, acc[0][1], 0, 0, 0);
    acc[1][0] = __builtin_amdgcn_mfma_f32_16x16x32_f16(af1, bf0, acc[1][0], 0, 0, 0);
    acc[1][1] = __builtin_amdgcn_mfma_f32_16x16x32_f16(af1, bf1, acc[1][1], 0, 0, 0);
  }
  #pragma unroll
  for (int mt = 0; mt < 2; mt++)
    #pragma unroll
    for (int nt = 0; nt < 2; nt++)
      #pragma unroll
      for (int i = 0; i < 4; i++)
        qpart[(ks * 32 + mt * 16 + lg * 4 + i) * 512 + n0 + nsub + nt * 16 + lr] = acc[mt][nt][i];
}

// attention per (h,b); fp16 K/V; writes attnres into xcT rows 0..511
__global__ __launch_bounds__(256) void kattn(const float* __restrict__ qpart,
    const float* __restrict__ qbc, const __half* __restrict__ Kb,
    const __half* __restrict__ Vb, float* __restrict__ xcT) {
  int h = blockIdx.x, b = blockIdx.y, t = threadIdx.x;
  __shared__ float qs[HD];
  __shared__ float sc[S_LEN];
  __shared__ float red[8];
  __shared__ float part[4][HD];
  if (t < HD) {
    int n = h * HD + t;
    float q = qbc[n];
    #pragma unroll
    for (int z = 0; z < 4; z++) q += qpart[(z * 32 + b) * DI + n];
    qs[t] = q;
  }
  __syncthreads();
  {
    const __half2* kr = reinterpret_cast<const __half2*>(Kb + (b * S_LEN + t) * DI + h * HD);
    float a = 0.f;
    #pragma unroll
    for (int d = 0; d < 32; d++) {
      float2 kf = __half22float2(kr[d]);
      a += qs[2 * d] * kf.x + qs[2 * d + 1] * kf.y;
    }
    sc[t] = a * 0.125f;
  }
  __syncthreads();
  float m = sc[t];
  for (int o = 32; o; o >>= 1) m = fmaxf(m, __shfl_xor(m, o));
  if ((t & 63) == 0) red[t >> 6] = m;
  __syncthreads();
  m = fmaxf(fmaxf(red[0], red[1]), fmaxf(red[2], red[3]));
  float p = __expf(sc[t] - m);
  float su = p;
  for (int o = 32; o; o >>= 1) su += __shfl_xor(su, o);
  if ((t & 63) == 0) red[4 + (t >> 6)] = su;
  sc[t] = p;
  __syncthreads();
  su = red[4] + red[5] + red[6] + red[7];
  {
    int d = t & 63, sg = t >> 6;
    const __half* vb = Vb + b * S_LEN * DI + h * HD + d;
    float a = 0.f;
    for (int s = sg * 64; s < sg * 64 + 64; s++) a += sc[s] * __half2float(vb[s * DI]);
    part[sg][d] = a;
  }
  __syncthreads();
  if (t < HD)
    xcT[(h * HD + t) * NB + b] = (part[0][t] + part[1][t] + part[2][t] + part[3][t]) / su;
}

// syn partials via MFMA: X(32x2560) @ synwT16. grid (64 nc, 10 ks)
__global__ __launch_bounds__(256) void ksyn(const float* __restrict__ xcT,
    const ushort* __restrict__ Wt, float* __restrict__ spp) {
  __shared__ __align__(16) _Float16 a16[32 * 280];
  __shared__ __align__(16) _Float16 w16[64 * 280];
  int nc = blockIdx.x, ks = blockIdx.y;
  int n0 = nc * 64, k0 = ks * 256;
  int t = threadIdx.x;
  {
    int row = t >> 2, q = t & 3;
    const uint4* g = reinterpret_cast<const uint4*>(Wt + (n0 + row) * 2560 + k0 + q * 64);
    uint4* ld = reinterpret_cast<uint4*>(&w16[row * 280 + q * 64]);
    #pragma unroll
    for (int u = 0; u < 8; u++) ld[u] = g[u];
  }
  for (int e = t; e < 8192; e += 256) {
    int kk = e >> 5, b = e & 31;
    a16[b * 280 + kk] = (_Float16)xcT[(k0 + kk) * 32 + b];
  }
  __syncthreads();
  int l = t & 63, w = t >> 6;
  int nsub = w * 16;
  int lr = l & 15, lg = l >> 4;
  f4 acc0 = {}, acc1 = {};
  #pragma unroll
  for (int s = 0; s < 8; s++) {
    h8 af0 = *(const h8*)&a16[lr * 280 + s * 32 + lg * 8];
    h8 af1 = *(const h8*)&a16[(16 + lr) * 280 + s * 32 + lg * 8];
    h8 bf  = *(const h8*)&w16[(nsub + lr) * 280 + s * 32 + lg * 8];
    acc0 = __builtin_amdgcn_mfma_f32_16x16x32_f16(af0, bf, acc0, 0, 0, 0);
    acc1 = __builtin_amdgcn_mfma_f32_16x16x32_f16(af1, bf, acc1, 0, 0, 0);
  }
  #pragma unroll
  for (int i = 0; i < 4; i++) {
    spp[(ks * 32 + lg * 4 + i) * 4096 + n0 + nsub + lr] = acc0[i];
    spp[(ks * 32 + 16 + lg * 4 + i) * 4096 + n0 + nsub + lr] = acc1[i];
  }
}

// sum partials + bias, GLU, LN -> ring slot. block per b
__global__ __launch_bounds__(256) void kglu(const float* __restrict__ spp,
    const float* __restrict__ bc, const float* __restrict__ lng,
    const float* __restrict__ lnb, float* __restrict__ ring, int slot) {
  int b = blockIdx.x, t = threadIdx.x;
  __shared__ float srow[4096];
  __shared__ float glu[2048];
  __shared__ float red[8];
  for (int n = t; n < 4096; n += 256) {
    float v = bc[n];
    #pragma unroll
    for (int ks = 0; ks < 10; ks++) v += spp[(ks * 32 + b) * 4096 + n];
    srow[n] = v;
  }
  __syncthreads();
  float s = 0.f, sq = 0.f;
  for (int d = t; d < 2048; d += 256) {
    float a = srow[d], g = srow[d + 2048];
    float gl = a / (1.f + __expf(-g));
    glu[d] = gl; s += gl; sq += gl * gl;
  }
  for (int o = 32; o; o >>= 1) { s += __shfl_xor(s, o); sq += __shfl_xor(sq, o); }
  if ((t & 63) == 0) { red[t >> 6] = s; red[4 + (t >> 6)] = sq; }
  __syncthreads();
  s = red[0] + red[1] + red[2] + red[3];
  sq = red[4] + red[5] + red[6] + red[7];
  float mean = s * (1.f / 2048.f);
  float var = sq * (1.f / 2048.f) - mean * mean;
  float rstd = rsqrtf(fmaxf(var, 0.f) + 1e-5f);
  for (int d = t; d < 2048; d += 256) {
    ring[(slot * 32 + b) * 2048 + d] = (glu[d] - mean) * rstd * lng[d] + lnb[d];
  }
}

// per-neuron NLM: fp16 LDS weights (bias folded m=25), fp32 math. grid 256
__global__ __launch_bounds__(256) void knlm(const float* __restrict__ ring,
    const uint* __restrict__ w1n, const float* __restrict__ w2t,
    const float* __restrict__ b2, float* __restrict__ xcT, int off) {
  __shared__ uint smem[26 * 512];       // phase1: trace fp32 (6400 f); phase2: weights
  __shared__ float w2s[1024];
  int blk = blockIdx.x;
  int d0 = blk * 8;
  int t = threadIdx.x;
  int dd = t >> 5, b = t & 31;
  float* trf32 = (float*)smem;
  for (int e = t; e < 800; e += 256) {
    int m = e >> 5, bb = e & 31;
    int slot = m + off; if (slot >= 25) slot -= 25;
    const float4* rp = (const float4*)&ring[(slot * 32 + bb) * 2048 + d0];
    float4 lo = rp[0], hi = rp[1];
    trf32[(0 * 25 + m) * 32 + bb] = lo.x; trf32[(1 * 25 + m) * 32 + bb] = lo.y;
    trf32[(2 * 25 + m) * 32 + bb] = lo.z; trf32[(3 * 25 + m) * 32 + bb] = lo.w;
    trf32[(4 * 25 + m) * 32 + bb] = hi.x; trf32[(5 * 25 + m) * 32 + bb] = hi.y;
    trf32[(6 * 25 + m) * 32 + bb] = hi.z; trf32[(7 * 25 + m) * 32 + bb] = hi.w;
  }
  __syncthreads();
  float trf[26];
  #pragma unroll
  for (int m = 0; m < 25; m++) trf[m] = trf32[(dd * 25 + m) * 32 + b];
  trf[25] = 1.f;
  __syncthreads();
  for (int e = t; e < 26 * 512; e += 256) {
    int m = e >> 9, r = e & 511;
    smem[e] = w1n[m * 131072 + d0 * 64 + r];
  }
  for (int e = t; e < 1024; e += 256) w2s[e] = w2t[blk * 1024 + e];
  __syncthreads();
  float p0 = 0.f, p1 = 0.f;
  for (int j = 0; j < 64; j++) {
    float hA = 0.f, hB = 0.f;
    #pragma unroll
    for (int m = 0; m < 26; m++) {
      uint u = smem[m * 512 + dd * 64 + j];
      __half2 h2 = *reinterpret_cast<const __half2*>(&u);
      float2 wf = __half22float2(h2);
      hA = fmaf(wf.x, trf[m], hA);
      hB = fmaf(wf.y, trf[m], hB);
    }
    float hg = hA / (1.f + __expf(-hB));
    p0 = fmaf(hg, w2s[dd * 128 + 2 * j], p0);
    p1 = fmaf(hg, w2s[dd * 128 + 2 * j + 1], p1);
  }
  int d = d0 + dd;
  float a0 = p0 + b2[2 * d], a1 = p1 + b2[2 * d + 1];
  xcT[(DI + d) * NB + b] = a0 / (1.f + __expf(-a1));
}

// fused sync_o update + pred partials via MFMA + atomic. grid (8 nc, 4 ks)
__global__ __launch_bounds__(256) void kout(const float* __restrict__ xcT,
    const float* __restrict__ dao_in, const float* __restrict__ dbo_in,
    float* __restrict__ dao_out, float* __restrict__ dbo_out,
    const float* __restrict__ ro, const int* __restrict__ iol,
    const int* __restrict__ ior, const ushort* __restrict__ Wt,
    float* __restrict__ predb, float* __restrict__ outS, int last) {
  __shared__ float so[128 * 32];
  __shared__ __align__(16) _Float16 a16[32 * 136];
  __shared__ __align__(16) _Float16 w16[128 * 136];
  int nc = blockIdx.x, ks = blockIdx.y;
  int k0 = ks * 128, n0 = nc * 128;
  int t = threadIdx.x;
  const float* actT = xcT + DI * NB;
  for (int e = t; e < 4096; e += 256) {
    int kk = e >> 5, b = e & 31;
    int k = k0 + kk;
    float dn = ro[k] * dao_in[k * 32 + b] + actT[iol[k] * 32 + b] * actT[ior[k] * 32 + b];
    float bn = ro[k] * dbo_in[k * 32 + b] + 1.f;
    float sv = dn * rsqrtf(bn);
    so[e] = sv;
    if (nc == 0) {
      dao_out[k * 32 + b] = dn; dbo_out[k * 32 + b] = bn;
      if (last) outS[b * 512 + k] = sv;
    }
  }
  {
    int row = t >> 1, hh = (t & 1) * 64;
    const uint4* g = reinterpret_cast<const uint4*>(Wt + (n0 + row) * 512 + k0 + hh);
    uint4* ld = reinterpret_cast<uint4*>(&w16[row * 136 + hh]);
    #pragma unroll
    for (int u = 0; u < 8; u++) ld[u] = g[u];
  }
  __syncthreads();
  for (int e = t; e < 4096; e += 256) {
    int kk = e >> 5, b = e & 31;
    a16[b * 136 + kk] = (_Float16)so[kk * 32 + b];
  }
  __syncthreads();
  int l = t & 63, w = t >> 6;
  int nsub = w * 32;
  int lr = l & 15, lg = l >> 4;
  f4 acc[2][2] = {};
  #pragma unroll
  for (int s = 0; s < 4; s++) {
    h8 af0 = *(const h8*)&a16[lr * 136 + s * 32 + lg * 8];
    h8 af1 = *(const h8*)&a16[(16 + lr) * 136 + s * 32 + lg * 8];
    h8 bf0 = *(const h8*)&w16[(nsub + lr) * 136 + s * 32 + lg * 8];
    h8 bf1 = *(const h8*)&w16[(nsub + 16 + lr) * 136 + s * 32 + lg * 8];
    acc[0][0] = __builtin_amdgcn_mfma_f32_16x16x32_f16(af0, bf0, acc[0][0], 0, 0, 0);
    acc[0][1] = __builtin_amdgcn_mfma_f32_16x16x32_f16(af0, bf1, acc[0][1], 0, 0, 0);
    acc[1][0] = __builtin_amdgcn_mfma_f32_16x16x32_f16(af1, bf0, acc[1][0], 0, 0, 0);
    acc[1][1] = __builtin_amdgcn_mfma_f32_16x16x32_f16(af1, bf1, acc[1][1], 0, 0, 0);
  }
  #pragma unroll
  for (int mt = 0; mt < 2; mt++)
    #pragma unroll
    for (int nt = 0; nt < 2; nt++)
      #pragma unroll
      for (int i = 0; i < 4; i++)
        atomicAdd(&predb[(mt * 16 + lg * 4 + i) * 1024 + n0 + nsub + nt * 16 + lr], acc[mt][nt][i]);
}

// predictions + entropy; re-init predb
__global__ __launch_bounds__(256) void kout2(float* __restrict__ predb,
    const float* __restrict__ outb, float* __restrict__ out, int it) {
  int b = blockIdx.x, t = threadIdx.x;
  __shared__ float pr[OD];
  __shared__ float red[12];
  for (int o = t; o < OD; o += 256) {
    float v = predb[b * 1024 + o];
    pr[o] = v;
    out[(b * OD + o) * NITER + it] = v;
  }
  __syncthreads();
  for (int o = t; o < OD; o += 256) predb[b * 1024 + o] = outb[o];
  float m = -1e30f;
  for (int o = t; o < OD; o += 256) m = fmaxf(m, pr[o]);
  for (int o = 32; o; o >>= 1) m = fmaxf(m, __shfl_xor(m, o));
  if ((t & 63) == 0) red[t >> 6] = m;
  __syncthreads();
  m = fmaxf(fmaxf(red[0], red[1]), fmaxf(red[2], red[3]));
  float s = 0.f, w = 0.f;
  for (int o = t; o < OD; o += 256) {
    float e = __expf(pr[o] - m);
    s += e; w += e * pr[o];
  }
  for (int o = 32; o; o >>= 1) { s += __shfl_xor(s, o); w += __shfl_xor(w, o); }
  if ((t & 63) == 0) { red[4 + (t >> 6)] = s; red[8 + (t >> 6)] = w; }
  __syncthreads();
  if (t == 0) {
    s = red[4] + red[5] + red[6] + red[7];
    w = red[8] + red[9] + red[10] + red[11];
    float lse = m + __logf(s);
    float ne = (lse - w / s) * (1.f / 6.907755278982137f);
    out[OFF_C + (b * 2) * NITER + it] = ne;
    out[OFF_C + (b * 2 + 1) * NITER + it] = 1.f - ne;
  }
}

// ================= host =================

extern "C" void kernel_launch(void* const* d_in, const int* in_sizes, int n_in,
                              void* d_out, int out_size, void* d_ws, size_t ws_size,
                              hipStream_t stream) {
  const float* x    = (const float*)d_in[0];
  const float* kvw  = (const float*)d_in[1];
  const float* kvb  = (const float*)d_in[2];
  const float* kvlg = (const float*)d_in[3];
  const float* kvlb = (const float*)d_in[4];
  const float* qw   = (const float*)d_in[5];
  const float* qb   = (const float*)d_in[6];
  const float* aw   = (const float*)d_in[7];
  const float* ab   = (const float*)d_in[8];
  const float* aow  = (const float*)d_in[9];
  const float* aob  = (const float*)d_in[10];
  const float* synw = (const float*)d_in[11];
  const float* synb = (const float*)d_in[12];
  const float* lng  = (const float*)d_in[13];
  const float* lnb  = (const float*)d_in[14];
  const float* tp1w = (const float*)d_in[15];
  const float* tp1b = (const float*)d_in[16];
  const float* tp2w = (const float*)d_in[17];
  const float* tp2b = (const float*)d_in[18];
  const float* sas  = (const float*)d_in[19];
  const float* strc = (const float*)d_in[20];
  const float* deca = (const float*)d_in[21];
  const float* deco = (const float*)d_in[22];
  const float* outw = (const float*)d_in[23];
  const float* outb = (const float*)d_in[24];
  const int* ial = (const int*)d_in[25];
  const int* iar = (const int*)d_in[26];
  const int* iol = (const int*)d_in[27];
  const int* ior = (const int*)d_in[28];
  float* out = (float*)d_out;
  float* ws = (float*)d_ws;

  // persistent regions (float units)
  float*  r0      = ws;                           // 4,194,304
  __half* Kb16    = (__half*)(ws + 4194304);      // 2,097,152 f
  __half* Vb16    = (__half*)(ws + 6291456);      // 2,097,152 f
  ushort* synwT16 = (ushort*)(ws + 8388608);      // 5,242,880 f
  ushort* qwcT16  = (ushort*)(ws + 13631488);     // 131,072 f
  ushort* outwT16 = (ushort*)(ws + 13762560);     // 262,144 f
  uint*   w1n     = (uint*)(ws + 14024704);       // 3,407,872 f
  float*  w2t     = ws + 17432576;                // 262,144 f
  // total 17,694,720 floats = 70.8 MB

  // r0 loop internals
  float* ring  = r0;                   // 1,638,400
  float* xcT   = r0 + 1638400;         // 81,920
  float* spp   = r0 + 1720320;         // 1,310,720
  float* qpart = r0 + 3031040;         // 65,536
  float* predb = r0 + 3096576;         // 32,768
  float* daaT  = r0 + 3129344;         // 32,768 (2 halves of 16,384)
  float* dbaT  = r0 + 3162112;
  float* daoT  = r0 + 3194880;
  float* dboT  = r0 + 3227648;
  float* ra    = r0 + 3260416;         // 512
  float* ro    = r0 + 3260928;         // 512
  float* bc    = r0 + 4186112;         // 4,096
  float* qbc   = r0 + 4190208;         // 512
  // setup temps (dead before kinit)
  float* kv    = r0;                   // full region during kkv8..kkvp16
  float* WcT   = r0;                   // 2,097,152
  float* qwT   = r0 + 2097152;         // 262,144
  float* awT   = r0 + 2359296;         // 262,144
  float* qwcF  = r0 + 2621440;         // 262,144

  // ---- setup ----
  kkv8<<<dim3(4, 2, 32), 256, 0, stream>>>(x, kvw, kvb, kv);
  kln<<<NB * S_LEN, 64, 0, stream>>>(kv, kvlg, kvlb);
  kkvp16<<<dim3(4, 64, 2), 256, 0, stream>>>(kv, aw, ab, Kb16, Vb16);
  // kv dead; folded weights
  ktrs<<<dim3(16, 16), 256, 0, stream>>>(qw, qwT, 512, 512);
  ktrs<<<dim3(16, 16), 256, 0, stream>>>(aw, awT, 512, 512);
  kgemmT<<<dim3(4, 4), 256, 0, stream>>>(awT, 512, qwT, 512, qwcF, 512, 512);   // qwcT[n][k]
  kcast16<<<256, 256, 0, stream>>>(qwcF, qwcT16, 262144);
  kgemmT<<<dim3(4, 32), 256, 0, stream>>>(synw, 4096, aow, 512, WcT, 512, 512); // WcT[n][j]
  kpackS<<<dim3(80, 128), 256, 0, stream>>>(WcT, synw, synwT16);
  koutw<<<dim3(16, 32), 256, 0, stream>>>(outw, outwT16);
  kbias<<<16, 256, 0, stream>>>(synw, aob, synb, bc);
  kqb<<<2, 256, 0, stream>>>(aw, ab, qb, qbc);
  kpack1<<<dim3(32, 4), 256, 0, stream>>>(tp1w, w1n);
  kpackB<<<512, 256, 0, stream>>>(tp1b, w1n);
  ktr2<<<32, 256, 0, stream>>>(tp2w, w2t);
  kinit<<<6400, 256, 0, stream>>>(sas, strc, deca, deco, iol, ior, outb,
                                  ring, xcT, daaT, dbaT, daoT, dboT, ra, ro, predb);

  // ---- iterations ----
  for (int it = 0; it < NITER; it++) {
    int p = it & 1;
    kq<<<dim3(4, 4), 256, 0, stream>>>(xcT, daaT + p * 16384, dbaT + p * 16384,
                                       daaT + (p ^ 1) * 16384, dbaT + (p ^ 1) * 16384,
                                       ra, ial, iar, qwcT16, qpart);
    kattn<<<dim3(NH, NB), 256, 0, stream>>>(qpart, qbc, Kb16, Vb16, xcT);
    ksyn<<<dim3(64, 10), 256, 0, stream>>>(xcT, synwT16, spp);
    kglu<<<NB, 256, 0, stream>>>(spp, bc, lng, lnb, ring, it % MEM);
    knlm<<<256, 256, 0, stream>>>(ring, w1n, w2t, tp2b, xcT, (it + 1) % MEM);
    kout<<<dim3(8, 4), 256, 0, stream>>>(xcT, daoT + p * 16384, dboT + p * 16384,
                                         daoT + (p ^ 1) * 16384, dboT + (p ^ 1) * 16384,
                                         ro, iol, ior, outwT16, predb, out + OFF_S,
                                         (it == NITER - 1) ? 1 : 0);
    kout2<<<NB, 256, 0, stream>>>(predb, outb, out, it);
  }
}

// Round 5
// 2352.928 us; speedup vs baseline: 4.3346x; 1.3488x over previous
//
#include <hip/hip_runtime.h>
#include <hip/hip_fp16.h>

#define NB 32
#define S_LEN 256
#define NITER 25
#define DM 2048
#define DI 512
#define NH 8
#define HD 64
#define NS 512
#define MEM 25
#define OD 1000

#define OFF_C 800000   // NB*OD*NITER
#define OFF_S 801600   // + NB*2*NITER

typedef _Float16 h8 __attribute__((ext_vector_type(8)));
typedef float f4 __attribute__((ext_vector_type(4)));

// ================= setup kernels =================

// transpose-cast: in fp32 [R][C] -> out fp16 [C][R]; z-batched with offsets
__global__ __launch_bounds__(256) void ktc(const float* __restrict__ in,
    _Float16* __restrict__ outp, int R, int C, int zIn, int zOut) {
  __shared__ float tl[32][33];
  int c0 = blockIdx.x * 32, r0 = blockIdx.y * 32;
  const float* ip = in + (size_t)blockIdx.z * zIn;
  _Float16* op = outp + (size_t)blockIdx.z * zOut;
  int t = threadIdx.x;
  for (int e = t; e < 1024; e += 256) {
    int rr = e >> 5, cc = e & 31;
    tl[rr][cc] = ip[(size_t)(r0 + rr) * C + c0 + cc];
  }
  __syncthreads();
  for (int e = t; e < 1024; e += 256) {
    int cc = e >> 5, rr = e & 31;
    op[(size_t)(c0 + cc) * R + r0 + rr] = (_Float16)tl[rr][cc];
  }
}

// flat cast fp32 -> fp16 (exact grid)
__global__ __launch_bounds__(256) void kc16(const float* __restrict__ in,
    _Float16* __restrict__ outp, int n) {
  int i = blockIdx.x * 256 + threadIdx.x;
  if (i < n) outp[i] = (_Float16)in[i];
}

// generic MFMA GEMM: C[m][n] = sum_k A[m][k]*B[n][k] (+bias[n]); out fp32 or fp16
__global__ __launch_bounds__(256) void mm16(const _Float16* __restrict__ A, int lda,
    const _Float16* __restrict__ B, int ldb, const float* __restrict__ bias,
    float* __restrict__ Cf, _Float16* __restrict__ Ch, int ldc, int K) {
  __shared__ __align__(16) _Float16 As[128 * 72];
  __shared__ __align__(16) _Float16 Bs[64 * 72];
  int n0 = blockIdx.x * 64, m0 = blockIdx.y * 128;
  int t = threadIdx.x;
  int l = t & 63, w = t >> 6, lr = l & 15, lg = l >> 4;
  f4 acc[2][4] = {};
  for (int k0 = 0; k0 < K; k0 += 64) {
    #pragma unroll
    for (int i = 0; i < 4; i++) {
      int idx = i * 256 + t; int row = idx >> 3, o8 = idx & 7;
      *(uint4*)&As[row * 72 + o8 * 8] = *(const uint4*)&A[(size_t)(m0 + row) * lda + k0 + o8 * 8];
    }
    #pragma unroll
    for (int i = 0; i < 2; i++) {
      int idx = i * 256 + t; int row = idx >> 3, o8 = idx & 7;
      *(uint4*)&Bs[row * 72 + o8 * 8] = *(const uint4*)&B[(size_t)(n0 + row) * ldb + k0 + o8 * 8];
    }
    __syncthreads();
    #pragma unroll
    for (int ks = 0; ks < 2; ks++) {
      h8 af0 = *(const h8*)&As[(w * 32 + lr) * 72 + ks * 32 + lg * 8];
      h8 af1 = *(const h8*)&As[(w * 32 + 16 + lr) * 72 + ks * 32 + lg * 8];
      #pragma unroll
      for (int nt = 0; nt < 4; nt++) {
        h8 bf = *(const h8*)&Bs[(nt * 16 + lr) * 72 + ks * 32 + lg * 8];
        acc[0][nt] = __builtin_amdgcn_mfma_f32_16x16x32_f16(af0, bf, acc[0][nt], 0, 0, 0);
        acc[1][nt] = __builtin_amdgcn_mfma_f32_16x16x32_f16(af1, bf, acc[1][nt], 0, 0, 0);
      }
    }
    __syncthreads();
  }
  #pragma unroll
  for (int mt = 0; mt < 2; mt++)
    #pragma unroll
    for (int nt = 0; nt < 4; nt++)
      #pragma unroll
      for (int i = 0; i < 4; i++) {
        int row = m0 + w * 32 + mt * 16 + lg * 4 + i;
        int col = n0 + nt * 16 + lr;
        float v = acc[mt][nt][i] + (bias ? bias[col] : 0.f);
        if (Cf) Cf[(size_t)row * ldc + col] = v;
        else    Ch[(size_t)row * ldc + col] = (_Float16)v;
      }
}

// in-place LN over last dim (512)
__global__ __launch_bounds__(64) void kln(float* __restrict__ kv,
    const float* __restrict__ g, const float* __restrict__ bb) {
  int row = blockIdx.x;
  int lane = threadIdx.x;
  const int base = row * DI;
  float v[8], s = 0.f, sq = 0.f;
  #pragma unroll
  for (int i = 0; i < 8; i++) {
    v[i] = kv[base + lane + i * 64];
    s += v[i]; sq += v[i] * v[i];
  }
  for (int o = 32; o; o >>= 1) { s += __shfl_xor(s, o); sq += __shfl_xor(sq, o); }
  float mean = s * (1.f / DI);
  float var = sq * (1.f / DI) - mean * mean;
  float rstd = rsqrtf(fmaxf(var, 0.f) + 1e-5f);
  #pragma unroll
  for (int i = 0; i < 8; i++) {
    int d = lane + i * 64;
    kv[base + d] = (v[i] - mean) * rstd * g[d] + bb[d];
  }
}

// synwT16[n][k] for k>=512: transpose-cast synw bottom rows
__global__ __launch_bounds__(256) void kpackS2(const float* __restrict__ synw,
    _Float16* __restrict__ outp) {
  __shared__ float tl[32][33];
  int k0 = 512 + blockIdx.x * 32, n0 = blockIdx.y * 32;
  int t = threadIdx.x;
  for (int e = t; e < 1024; e += 256) {
    int rr = e >> 5, cc = e & 31;
    tl[rr][cc] = synw[(size_t)(k0 + rr) * 4096 + n0 + cc];
  }
  __syncthreads();
  for (int e = t; e < 1024; e += 256) {
    int cc = e >> 5, rr = e & 31;
    outp[(size_t)(n0 + cc) * 2560 + k0 + rr] = (_Float16)tl[rr][cc];
  }
}

// outwT16[o(1024 pad)][k(512)] from outw[k][1000]
__global__ __launch_bounds__(256) void koutw(const float* __restrict__ outw,
    _Float16* __restrict__ outp) {
  __shared__ float tl[32][33];
  int k0 = blockIdx.x * 32, o0 = blockIdx.y * 32;
  int t = threadIdx.x;
  for (int e = t; e < 1024; e += 256) {
    int rr = e >> 5, cc = e & 31;
    tl[rr][cc] = (o0 + cc < OD) ? outw[(size_t)(k0 + rr) * OD + o0 + cc] : 0.f;
  }
  __syncthreads();
  for (int e = t; e < 1024; e += 256) {
    int cc = e >> 5, rr = e & 31;
    outp[(size_t)(o0 + cc) * 512 + k0 + rr] = (_Float16)tl[rr][cc];
  }
}

// bc[n] = synb[n] + sum_j aob[j]*synw[j][n]
__global__ __launch_bounds__(256) void kbias(const float* __restrict__ synw,
    const float* __restrict__ aob, const float* __restrict__ synb,
    float* __restrict__ bc) {
  int n = blockIdx.x * 256 + threadIdx.x;
  float acc = synb[n];
  for (int j = 0; j < 512; j++) acc += aob[j] * synw[(size_t)j * 4096 + n];
  bc[n] = acc;
}

// qbc[n] = ab[n] + sum_m qb[m]*aw[n][m]
__global__ __launch_bounds__(256) void kqb(const float* __restrict__ aw,
    const float* __restrict__ ab, const float* __restrict__ qb,
    float* __restrict__ qbc) {
  int n = blockIdx.x * 256 + threadIdx.x;
  float acc = ab[n];
  for (int m = 0; m < 512; m++) acc += qb[m] * aw[n * 512 + m];
  qbc[n] = acc;
}

// w1k[d][j(128)][m(32)] fp16: m<25 = tp1w[m][j][d], m==25 = tp1b[d][j], else 0
__global__ __launch_bounds__(256) void kpackW1K(const float* __restrict__ w1,
    const float* __restrict__ b1, _Float16* __restrict__ w1k) {
  __shared__ float tl[25][512];     // [m][j*4+dd]
  int d0 = blockIdx.x * 4;
  int t = threadIdx.x;
  for (int e = t; e < 12800; e += 256) {
    int m = e >> 9;
    int rem = e & 511;
    int j = rem >> 2, dd = rem & 3;
    tl[m][j * 4 + dd] = w1[((size_t)(m * 128 + j)) * DM + d0 + dd];
  }
  __syncthreads();
  uint* wo = (uint*)w1k;
  for (int e2 = t; e2 < 8192; e2 += 256) {
    int dd = e2 >> 11, j = (e2 >> 4) & 127, mp = e2 & 15;
    int m0 = 2 * mp, m1 = 2 * mp + 1;
    float v0 = (m0 < 25) ? tl[m0][j * 4 + dd] : 0.f;
    float v1 = (m1 < 25) ? tl[m1][j * 4 + dd]
             : ((m1 == 25) ? b1[(d0 + dd) * 128 + j] : 0.f);
    __half2 h2 = __floats2half2_rn(v0, v1);
    wo[(size_t)(d0 + dd) * 2048 + j * 16 + mp] = *reinterpret_cast<uint*>(&h2);
  }
}

// tp2_w (64,2,2048) -> w2t[d][j*2+c] fp32
__global__ __launch_bounds__(256) void ktr2(const float* __restrict__ w2, float* __restrict__ w2t) {
  __shared__ float tile[128][65];
  int d0 = blockIdx.x * 64;
  int t = threadIdx.x;
  for (int e = t; e < 8192; e += 256) {
    int row = e >> 6, dd = e & 63;
    tile[row][dd] = w2[row * DM + d0 + dd];
  }
  __syncthreads();
  for (int e = t; e < 8192; e += 256) {
    int dd = e >> 7, row = e & 127;
    w2t[(d0 + dd) * 128 + row] = tile[row][dd];
  }
}

// init dynamic state (last setup kernel)
__global__ __launch_bounds__(256) void kinit(const float* __restrict__ sas,
    const float* __restrict__ strc, const float* __restrict__ deca,
    const float* __restrict__ deco, const int* __restrict__ iol,
    const int* __restrict__ ior,
    float* __restrict__ ring, float* __restrict__ xcT,
    float* __restrict__ daaT, float* __restrict__ dbaT,
    float* __restrict__ daoT, float* __restrict__ dboT,
    float* __restrict__ ra, float* __restrict__ ro) {
  int idx = blockIdx.x * 256 + threadIdx.x;
  int stride = gridDim.x * 256;
  for (int i = idx; i < MEM * NB * DM; i += stride) {
    int m = i >> 16;
    int d = i & 2047;
    ring[i] = strc[d * MEM + m];
  }
  for (int i = idx; i < DM * NB; i += stride) {
    int d = i >> 5;
    xcT[(DI + d) * NB + (i & 31)] = sas[d];
  }
  for (int i = idx; i < NS * NB; i += stride) {
    int k = i >> 5;
    daaT[i] = 0.f; dbaT[i] = 0.f;
    daoT[i] = sas[iol[k]] * sas[ior[k]];
    dboT[i] = 1.f;
  }
  for (int i = idx; i < NS; i += stride) {
    ra[i] = __expf(-fminf(fmaxf(deca[i], 0.f), 15.f));
    ro[i] = __expf(-fminf(fmaxf(deco[i], 0.f), 15.f));
  }
}

// ================= per-iteration kernels =================

// fused: sync_a update + q (64-wide GEMV) + attention for (h,b)
__global__ __launch_bounds__(256) void kqattn(const float* __restrict__ xcT,
    const float* __restrict__ daa_in, const float* __restrict__ dba_in,
    float* __restrict__ daa_out, float* __restrict__ dba_out,
    const float* __restrict__ ra, const int* __restrict__ ial,
    const int* __restrict__ iar, const _Float16* __restrict__ qwcT,
    const float* __restrict__ qbc, const _Float16* __restrict__ Kb,
    const _Float16* __restrict__ Vb, float* __restrict__ xcTo) {
  int h = blockIdx.x, b = blockIdx.y, t = threadIdx.x;
  __shared__ float sa[NS];
  __shared__ float qp[4][64];
  __shared__ float qs[HD];
  __shared__ float sc[S_LEN];
  __shared__ float red[8];
  __shared__ float part[4][HD];
  const float* actT = xcT + DI * NB;
  for (int k = t; k < NS; k += 256) {
    float dn = ra[k] * daa_in[k * 32 + b] + actT[ial[k] * 32 + b] * actT[iar[k] * 32 + b];
    float bn = ra[k] * dba_in[k * 32 + b] + 1.f;
    sa[k] = dn * rsqrtf(bn);
    if (h == 0) { daa_out[k * 32 + b] = dn; dba_out[k * 32 + b] = bn; }
  }
  __syncthreads();
  {
    int n = t & 63, ks = t >> 6;
    const _Float16* wr = qwcT + (size_t)(h * 64 + n) * 512 + ks * 128;
    float acc = 0.f;
    for (int kk = 0; kk < 128; kk += 8) {
      h8 wv = *(const h8*)&wr[kk];
      #pragma unroll
      for (int u = 0; u < 8; u++) acc += (float)wv[u] * sa[ks * 128 + kk + u];
    }
    qp[ks][n] = acc;
  }
  __syncthreads();
  if (t < HD) qs[t] = qbc[h * HD + t] + qp[0][t] + qp[1][t] + qp[2][t] + qp[3][t];
  __syncthreads();
  {
    const __half2* kr = reinterpret_cast<const __half2*>(Kb + (size_t)(b * S_LEN + t) * DI + h * HD);
    float a = 0.f;
    #pragma unroll
    for (int d = 0; d < 32; d++) {
      float2 kf = __half22float2(kr[d]);
      a += qs[2 * d] * kf.x + qs[2 * d + 1] * kf.y;
    }
    sc[t] = a * 0.125f;
  }
  __syncthreads();
  float m = sc[t];
  for (int o = 32; o; o >>= 1) m = fmaxf(m, __shfl_xor(m, o));
  if ((t & 63) == 0) red[t >> 6] = m;
  __syncthreads();
  m = fmaxf(fmaxf(red[0], red[1]), fmaxf(red[2], red[3]));
  float p = __expf(sc[t] - m);
  float su = p;
  for (int o = 32; o; o >>= 1) su += __shfl_xor(su, o);
  if ((t & 63) == 0) red[4 + (t >> 6)] = su;
  sc[t] = p;
  __syncthreads();
  su = red[4] + red[5] + red[6] + red[7];
  {
    int d = t & 63, sg = t >> 6;
    const _Float16* vb = Vb + (size_t)b * S_LEN * DI + h * HD + d;
    float a = 0.f;
    for (int s = sg * 64; s < sg * 64 + 64; s++) a += sc[s] * (float)vb[s * DI];
    part[sg][d] = a;
  }
  __syncthreads();
  if (t < HD)
    xcTo[(h * HD + t) * NB + b] = (part[0][t] + part[1][t] + part[2][t] + part[3][t]) / su;
}

// syn partials via MFMA: X(32x2560) @ synwT16. grid (64 nc, 10 ks)
__global__ __launch_bounds__(256) void ksyn(const float* __restrict__ xcT,
    const ushort* __restrict__ Wt, float* __restrict__ spp) {
  __shared__ __align__(16) _Float16 a16[32 * 280];
  __shared__ __align__(16) _Float16 w16[64 * 280];
  int nc = blockIdx.x, ks = blockIdx.y;
  int n0 = nc * 64, k0 = ks * 256;
  int t = threadIdx.x;
  {
    int row = t >> 2, q = t & 3;
    const uint4* g = reinterpret_cast<const uint4*>(Wt + (size_t)(n0 + row) * 2560 + k0 + q * 64);
    uint4* ld = reinterpret_cast<uint4*>(&w16[row * 280 + q * 64]);
    #pragma unroll
    for (int u = 0; u < 8; u++) ld[u] = g[u];
  }
  for (int e = t; e < 8192; e += 256) {
    int kk = e >> 5, b = e & 31;
    a16[b * 280 + kk] = (_Float16)xcT[(k0 + kk) * 32 + b];
  }
  __syncthreads();
  int l = t & 63, w = t >> 6;
  int nsub = w * 16;
  int lr = l & 15, lg = l >> 4;
  f4 acc0 = {}, acc1 = {};
  #pragma unroll
  for (int s = 0; s < 8; s++) {
    h8 af0 = *(const h8*)&a16[lr * 280 + s * 32 + lg * 8];
    h8 af1 = *(const h8*)&a16[(16 + lr) * 280 + s * 32 + lg * 8];
    h8 bf  = *(const h8*)&w16[(nsub + lr) * 280 + s * 32 + lg * 8];
    acc0 = __builtin_amdgcn_mfma_f32_16x16x32_f16(af0, bf, acc0, 0, 0, 0);
    acc1 = __builtin_amdgcn_mfma_f32_16x16x32_f16(af1, bf, acc1, 0, 0, 0);
  }
  #pragma unroll
  for (int i = 0; i < 4; i++) {
    spp[(size_t)(ks * 32 + lg * 4 + i) * 4096 + n0 + nsub + lr] = acc0[i];
    spp[(size_t)(ks * 32 + 16 + lg * 4 + i) * 4096 + n0 + nsub + lr] = acc1[i];
  }
}

// sum partials + bias, GLU, LN -> ring slot. block per b
__global__ __launch_bounds__(256) void kglu(const float* __restrict__ spp,
    const float* __restrict__ bc, const float* __restrict__ lng,
    const float* __restrict__ lnb, float* __restrict__ ring, int slot) {
  int b = blockIdx.x, t = threadIdx.x;
  __shared__ float srow[4096];
  __shared__ float glu[2048];
  __shared__ float red[8];
  for (int n = t; n < 4096; n += 256) {
    float v = bc[n];
    #pragma unroll
    for (int ks = 0; ks < 10; ks++) v += spp[(size_t)(ks * 32 + b) * 4096 + n];
    srow[n] = v;
  }
  __syncthreads();
  float s = 0.f, sq = 0.f;
  for (int d = t; d < 2048; d += 256) {
    float a = srow[d], g = srow[d + 2048];
    float gl = a / (1.f + __expf(-g));
    glu[d] = gl; s += gl; sq += gl * gl;
  }
  for (int o = 32; o; o >>= 1) { s += __shfl_xor(s, o); sq += __shfl_xor(sq, o); }
  if ((t & 63) == 0) { red[t >> 6] = s; red[4 + (t >> 6)] = sq; }
  __syncthreads();
  s = red[0] + red[1] + red[2] + red[3];
  sq = red[4] + red[5] + red[6] + red[7];
  float mean = s * (1.f / 2048.f);
  float var = sq * (1.f / 2048.f) - mean * mean;
  float rstd = rsqrtf(fmaxf(var, 0.f) + 1e-5f);
  for (int d = t; d < 2048; d += 256) {
    ring[(size_t)(slot * 32 + b) * 2048 + d] = (glu[d] - mean) * rstd * lng[d] + lnb[d];
  }
}

// per-neuron NLM via MFMA: grid 512 (4 d/block, 1 d/wave)
__global__ __launch_bounds__(256) void knlm(const float* __restrict__ ring,
    const _Float16* __restrict__ w1k, const float* __restrict__ w2t,
    const float* __restrict__ b2, float* __restrict__ xcT, int off) {
  __shared__ __align__(16) _Float16 tr16[4 * 32 * 40];
  int d0 = blockIdx.x * 4;
  int t = threadIdx.x;
  for (int e = t; e < 800; e += 256) {
    int m = e >> 5, bb = e & 31;
    int slot = m + off; if (slot >= 25) slot -= 25;
    float4 v = *(const float4*)&ring[(size_t)(slot * 32 + bb) * 2048 + d0];
    tr16[(0 * 32 + bb) * 40 + m] = (_Float16)v.x;
    tr16[(1 * 32 + bb) * 40 + m] = (_Float16)v.y;
    tr16[(2 * 32 + bb) * 40 + m] = (_Float16)v.z;
    tr16[(3 * 32 + bb) * 40 + m] = (_Float16)v.w;
  }
  for (int e = t; e < 4 * 32 * 15; e += 256) {
    int dl = e / 480; int r = e - dl * 480; int bb = r / 15; int mm = 25 + (r % 15);
    tr16[(dl * 32 + bb) * 40 + mm] = (mm == 25) ? (_Float16)1.f : (_Float16)0.f;
  }
  __syncthreads();
  int l = t & 63, w = t >> 6;
  int lr = l & 15, lg = l >> 4;
  int d = d0 + w;
  const _Float16* wp = w1k + (size_t)d * 4096;
  h8 bf[8];
  #pragma unroll
  for (int nt = 0; nt < 8; nt++) bf[nt] = *(const h8*)&wp[(nt * 16 + lr) * 32 + lg * 8];
  h8 af0 = *(const h8*)&tr16[(w * 32 + lr) * 40 + lg * 8];
  h8 af1 = *(const h8*)&tr16[(w * 32 + 16 + lr) * 40 + lg * 8];
  f4 acc[2][8] = {};
  #pragma unroll
  for (int nt = 0; nt < 8; nt++) {
    acc[0][nt] = __builtin_amdgcn_mfma_f32_16x16x32_f16(af0, bf[nt], acc[0][nt], 0, 0, 0);
    acc[1][nt] = __builtin_amdgcn_mfma_f32_16x16x32_f16(af1, bf[nt], acc[1][nt], 0, 0, 0);
  }
  float w20[4], w21[4];
  #pragma unroll
  for (int nt = 0; nt < 4; nt++) {
    w20[nt] = w2t[d * 128 + 2 * (nt * 16 + lr)];
    w21[nt] = w2t[d * 128 + 2 * (nt * 16 + lr) + 1];
  }
  float b20 = b2[2 * d], b21 = b2[2 * d + 1];
  #pragma unroll
  for (int mt = 0; mt < 2; mt++)
    #pragma unroll
    for (int i = 0; i < 4; i++) {
      float p0 = 0.f, p1 = 0.f;
      #pragma unroll
      for (int nt = 0; nt < 4; nt++) {
        float a = acc[mt][nt][i], g = acc[mt][nt + 4][i];
        float hg = a / (1.f + __expf(-g));
        p0 = fmaf(hg, w20[nt], p0);
        p1 = fmaf(hg, w21[nt], p1);
      }
      p0 += __shfl_xor(p0, 1); p1 += __shfl_xor(p1, 1);
      p0 += __shfl_xor(p0, 2); p1 += __shfl_xor(p1, 2);
      p0 += __shfl_xor(p0, 4); p1 += __shfl_xor(p1, 4);
      p0 += __shfl_xor(p0, 8); p1 += __shfl_xor(p1, 8);
      float a0 = p0 + b20, a1 = p1 + b21;
      if (lr == 0)
        xcT[(DI + d) * NB + mt * 16 + lg * 4 + i] = a0 / (1.f + __expf(-a1));
    }
}

// fused: sync_o update + pred GEMV + entropy. block per b
__global__ __launch_bounds__(256) void koutf(const float* __restrict__ xcT,
    const float* __restrict__ dao_in, const float* __restrict__ dbo_in,
    float* __restrict__ dao_out, float* __restrict__ dbo_out,
    const float* __restrict__ ro, const int* __restrict__ iol,
    const int* __restrict__ ior, const _Float16* __restrict__ outwT,
    const float* __restrict__ outb, float* __restrict__ out,
    float* __restrict__ outS, int it, int last) {
  int b = blockIdx.x, t = threadIdx.x;
  __shared__ float so[NS];
  __shared__ float pr[OD];
  __shared__ float red[12];
  const float* actT = xcT + DI * NB;
  for (int k = t; k < NS; k += 256) {
    float dn = ro[k] * dao_in[k * 32 + b] + actT[iol[k] * 32 + b] * actT[ior[k] * 32 + b];
    float bn = ro[k] * dbo_in[k * 32 + b] + 1.f;
    float sv = dn * rsqrtf(bn);
    so[k] = sv;
    dao_out[k * 32 + b] = dn; dbo_out[k * 32 + b] = bn;
    if (last) outS[b * 512 + k] = sv;
  }
  __syncthreads();
  for (int o = t; o < OD; o += 256) {
    const _Float16* wr = outwT + (size_t)o * 512;
    float acc = outb[o];
    for (int kk = 0; kk < 512; kk += 8) {
      h8 wv = *(const h8*)&wr[kk];
      #pragma unroll
      for (int u = 0; u < 8; u++) acc += (float)wv[u] * so[kk + u];
    }
    pr[o] = acc;
    out[(b * OD + o) * NITER + it] = acc;
  }
  __syncthreads();
  float m = -1e30f;
  for (int o = t; o < OD; o += 256) m = fmaxf(m, pr[o]);
  for (int o = 32; o; o >>= 1) m = fmaxf(m, __shfl_xor(m, o));
  if ((t & 63) == 0) red[t >> 6] = m;
  __syncthreads();
  m = fmaxf(fmaxf(red[0], red[1]), fmaxf(red[2], red[3]));
  float s = 0.f, w = 0.f;
  for (int o = t; o < OD; o += 256) {
    float e = __expf(pr[o] - m);
    s += e; w += e * pr[o];
  }
  for (int o = 32; o; o >>= 1) { s += __shfl_xor(s, o); w += __shfl_xor(w, o); }
  if ((t & 63) == 0) { red[4 + (t >> 6)] = s; red[8 + (t >> 6)] = w; }
  __syncthreads();
  if (t == 0) {
    s = red[4] + red[5] + red[6] + red[7];
    w = red[8] + red[9] + red[10] + red[11];
    float lse = m + __logf(s);
    float ne = (lse - w / s) * (1.f / 6.907755278982137f);
    out[OFF_C + (b * 2) * NITER + it] = ne;
    out[OFF_C + (b * 2 + 1) * NITER + it] = 1.f - ne;
  }
}

// ================= host =================

extern "C" void kernel_launch(void* const* d_in, const int* in_sizes, int n_in,
                              void* d_out, int out_size, void* d_ws, size_t ws_size,
                              hipStream_t stream) {
  const float* x    = (const float*)d_in[0];
  const float* kvw  = (const float*)d_in[1];
  const float* kvb  = (const float*)d_in[2];
  const float* kvlg = (const float*)d_in[3];
  const float* kvlb = (const float*)d_in[4];
  const float* qw   = (const float*)d_in[5];
  const float* qb   = (const float*)d_in[6];
  const float* aw   = (const float*)d_in[7];
  const float* ab   = (const float*)d_in[8];
  const float* aow  = (const float*)d_in[9];
  const float* aob  = (const float*)d_in[10];
  const float* synw = (const float*)d_in[11];
  const float* synb = (const float*)d_in[12];
  const float* lng  = (const float*)d_in[13];
  const float* lnb  = (const float*)d_in[14];
  const float* tp1w = (const float*)d_in[15];
  const float* tp1b = (const float*)d_in[16];
  const float* tp2w = (const float*)d_in[17];
  const float* tp2b = (const float*)d_in[18];
  const float* sas  = (const float*)d_in[19];
  const float* strc = (const float*)d_in[20];
  const float* deca = (const float*)d_in[21];
  const float* deco = (const float*)d_in[22];
  const float* outw = (const float*)d_in[23];
  const float* outb = (const float*)d_in[24];
  const int* ial = (const int*)d_in[25];
  const int* iar = (const int*)d_in[26];
  const int* iol = (const int*)d_in[27];
  const int* ior = (const int*)d_in[28];
  float* out = (float*)d_out;
  float* ws = (float*)d_ws;

  // persistent regions (float units)
  float*     r0       = ws;                              // 4,194,304
  float*     kvf      = ws + 4194304;                    // 4,194,304 (setup only)
  _Float16*  Kb16     = (_Float16*)(ws + 4194304);       // 4,194,304 halfs (aliases kvf)
  _Float16*  Vb16     = (_Float16*)(ws + 6291456);       // 4,194,304 halfs
  _Float16*  synwT16  = (_Float16*)(ws + 8388608);       // 10,485,760 halfs
  _Float16*  qwcT16   = (_Float16*)(ws + 13631488);      // 262,144 halfs
  _Float16*  outwT16  = (_Float16*)(ws + 13762560);      // 524,288 halfs
  _Float16*  w1k      = (_Float16*)(ws + 14024704);      // 8,388,608 halfs
  float*     w2t      = ws + 18219008;                   // 262,144
  _Float16*  awh      = (_Float16*)(ws + 18481152);      // 786,432 halfs
  _Float16*  qwh      = (_Float16*)(ws + 18874368);      // 262,144 halfs
  _Float16*  awoT16   = (_Float16*)(ws + 19005440);      // 262,144 halfs
  _Float16*  synwTc16 = (_Float16*)(ws + 19136512);      // 2,097,152 halfs
  // total 20,185,088 floats = 80.7 MB

  // r0 setup temps (dead before kinit)
  _Float16* xT16  = (_Float16*)r0;                  // 4,194,304 halfs
  _Float16* kvh16 = (_Float16*)(r0 + 2097152);      // 4,194,304 halfs

  // r0 loop internals
  float* ring  = r0;                   // 1,638,400
  float* xcT   = r0 + 1638400;         // 81,920
  float* spp   = r0 + 1720320;         // 1,310,720
  float* daaT  = r0 + 3129344;         // 2 halves of 16,384
  float* dbaT  = r0 + 3162112;
  float* daoT  = r0 + 3194880;
  float* dboT  = r0 + 3227648;
  float* ra    = r0 + 3260416;         // 512
  float* ro    = r0 + 3260928;         // 512
  float* bc    = r0 + 4186112;         // 4,096
  float* qbc   = r0 + 4190208;         // 512

  // ---- setup ----
  ktc<<<dim3(8, 16, 32), 256, 0, stream>>>(x, xT16, 512, 256, 131072, 131072);
  ktc<<<dim3(16, 16, 1), 256, 0, stream>>>(kvw, (_Float16*)(r0 + 4063232), 512, 512, 0, 0); // kvwT16 temp (top of r0)
  _Float16* kvwT16 = (_Float16*)(r0 + 4063232);   // 262,144 halfs at r0[4,063,232..4,194,304)... overlaps bc/qbc region? bc at 4,186,112 — conflict!
  // move kvwT16 into S2 scratch instead: reuse qwh region before qw cast
  kvwT16 = qwh;   // qwh not yet written
  ktc<<<dim3(16, 16, 1), 256, 0, stream>>>(kvw, kvwT16, 512, 512, 0, 0);
  mm16<<<dim3(8, 64), 256, 0, stream>>>(xT16, 512, kvwT16, 512, kvb, kvf, nullptr, 512, 512);
  kln<<<NB * S_LEN, 64, 0, stream>>>(kvf, kvlg, kvlb);
  kc16<<<16384, 256, 0, stream>>>(kvf, kvh16, 4194304);
  kc16<<<3072, 256, 0, stream>>>(aw, awh, 786432);
  mm16<<<dim3(8, 64), 256, 0, stream>>>(kvh16, 512, awh + 512 * 512, 512, ab + 512, nullptr, Kb16, 512, 512);
  mm16<<<dim3(8, 64), 256, 0, stream>>>(kvh16, 512, awh + 1024 * 512, 512, ab + 1024, nullptr, Vb16, 512, 512);
  kc16<<<1024, 256, 0, stream>>>(qw, qwh, 262144);   // overwrites kvwT16 (dead)
  mm16<<<dim3(8, 4), 256, 0, stream>>>(awh, 512, qwh, 512, nullptr, nullptr, qwcT16, 512, 512);
  ktc<<<dim3(16, 16, 1), 256, 0, stream>>>(aow, awoT16, 512, 512, 0, 0);
  ktc<<<dim3(128, 16, 1), 256, 0, stream>>>(synw, synwTc16, 512, 4096, 0, 0);
  mm16<<<dim3(8, 32), 256, 0, stream>>>(synwTc16, 512, awoT16, 512, nullptr, nullptr, synwT16, 2560, 512);
  kpackS2<<<dim3(64, 128), 256, 0, stream>>>(synw, synwT16);
  koutw<<<dim3(16, 32), 256, 0, stream>>>(outw, outwT16);
  kbias<<<16, 256, 0, stream>>>(synw, aob, synb, bc);
  kqb<<<2, 256, 0, stream>>>(aw, ab, qb, qbc);
  kpackW1K<<<512, 256, 0, stream>>>(tp1w, tp1b, w1k);
  ktr2<<<32, 256, 0, stream>>>(tp2w, w2t);
  kinit<<<2048, 256, 0, stream>>>(sas, strc, deca, deco, iol, ior,
                                  ring, xcT, daaT, dbaT, daoT, dboT, ra, ro);

  // ---- iterations ----
  for (int it = 0; it < NITER; it++) {
    int p = it & 1;
    kqattn<<<dim3(NH, NB), 256, 0, stream>>>(xcT, daaT + p * 16384, dbaT + p * 16384,
                                             daaT + (p ^ 1) * 16384, dbaT + (p ^ 1) * 16384,
                                             ra, ial, iar, qwcT16, qbc, Kb16, Vb16, xcT);
    ksyn<<<dim3(64, 10), 256, 0, stream>>>(xcT, (const ushort*)synwT16, spp);
    kglu<<<NB, 256, 0, stream>>>(spp, bc, lng, lnb, ring, it % MEM);
    knlm<<<512, 256, 0, stream>>>(ring, w1k, w2t, tp2b, xcT, (it + 1) % MEM);
    koutf<<<NB, 256, 0, stream>>>(xcT, daoT + p * 16384, dboT + p * 16384,
                                  daoT + (p ^ 1) * 16384, dboT + (p ^ 1) * 16384,
                                  ro, iol, ior, outwT16, outb, out, out + OFF_S,
                                  it, (it == NITER - 1) ? 1 : 0);
  }
}